// Round 1
// baseline (3425.021 us; speedup 1.0000x reference)
//
#include <hip/hip_runtime.h>

#define NC 100000
#define NW 500
#define NE_CC 600000
#define NE_CW 25000
#define H 128
#define NL 3
#define DFF 512

__device__ __forceinline__ float wsum(float v){
  #pragma unroll
  for (int o = 32; o; o >>= 1) v += __shfl_xor(v, o, 64);
  return v;
}
__device__ __forceinline__ unsigned fenc(float f){
  unsigned u = __float_as_uint(f);
  return (u & 0x80000000u) ? ~u : (u | 0x80000000u);
}
__device__ __forceinline__ float fdec(unsigned u){
  u = (u & 0x80000000u) ? (u ^ 0x80000000u) : ~u;
  return __uint_as_float(u);
}

// ---------- embeddings: h = x @ W + b,  W staged in LDS ----------
template<int K>
__global__ __launch_bounds__(256) void embed_k(const float* __restrict__ x,
    const float* __restrict__ W, const float* __restrict__ b,
    float* __restrict__ h, int M)
{
  __shared__ float sW[K * 128];
  for (int t = threadIdx.x; t < K * 128; t += 256) sW[t] = W[t];
  __syncthreads();
  int j = threadIdx.x & 127, half = threadIdx.x >> 7;
  float bj = b[j];
  for (int n = blockIdx.x * 2 + half; n < M; n += gridDim.x * 2){
    const float* xr = x + (size_t)n * K;
    float acc = bj;
    #pragma unroll
    for (int k = 0; k < K; k++) acc += xr[k] * sW[k * 128 + j];
    h[(size_t)n * H + j] = acc;
  }
}

// ---------- per-layer scalar edge coefficients ----------
__global__ void coeff_k(const float* __restrict__ gWe, const float* __restrict__ gae,
    const float* __restrict__ Wee, const float* __restrict__ bee, float* __restrict__ coeff)
{
  __shared__ float red[4];
  int t = threadIdx.x;  // 0..127
  for (int i = 0; i < NL; i++){
    const float* Wr = gWe + ((size_t)i * H + t) * H;
    const float* ga = gae + (size_t)i * H;
    float w = 0.f;
    for (int k = 0; k < H; k++) w += Wr[k] * ga[k];
    float pc = Wee[t] * w, pd = bee[t] * w;
    pc = wsum(pc); pd = wsum(pd);
    if ((t & 63) == 0){ red[(t >> 6) * 2 + 0] = pc; red[(t >> 6) * 2 + 1] = pd; }
    __syncthreads();
    if (t == 0){ coeff[i] = red[0] + red[2]; coeff[NL + i] = red[1] + red[3]; }
    __syncthreads();
  }
}

// ---------- LayerNorm (wave per node); optional pre-add + writeback ----------
__global__ __launch_bounds__(256) void ln_k(const float* __restrict__ hin,
    float* __restrict__ hout, const float* __restrict__ g, const float* __restrict__ b,
    const float* __restrict__ addv, float* __restrict__ xn, int M)
{
  int lane = threadIdx.x & 63, wid = threadIdx.x >> 6;
  int n = blockIdx.x * 4 + wid;
  if (n >= M) return;
  const float* row = hin + (size_t)n * H;
  float x0 = row[lane], x1 = row[lane + 64];
  if (addv){ x0 += addv[lane]; x1 += addv[lane + 64]; }
  float mu = wsum(x0 + x1) * (1.f / H);
  float d0 = x0 - mu, d1 = x1 - mu;
  float var = wsum(d0 * d0 + d1 * d1) * (1.f / H);
  float rs = rsqrtf(var + 1e-5f);
  if (hout){ hout[(size_t)n * H + lane] = x0; hout[(size_t)n * H + lane + 64] = x1; }
  xn[(size_t)n * H + lane]      = d0 * rs * g[lane]      + b[lane];
  xn[(size_t)n * H + lane + 64] = d1 * rs * g[lane + 64] + b[lane + 64];
}

// ---------- dual dot products per node ----------
__global__ __launch_bounds__(256) void dot2_k(const float* __restrict__ X,
    const float* __restrict__ va, const float* __restrict__ vb,
    float* __restrict__ oa, float* __restrict__ ob, int M)
{
  int lane = threadIdx.x & 63, wid = threadIdx.x >> 6;
  int n = blockIdx.x * 4 + wid;
  if (n >= M) return;
  const float* row = X + (size_t)n * H;
  float x0 = row[lane], x1 = row[lane + 64];
  float a = wsum(x0 * va[lane] + x1 * va[lane + 64]);
  if (lane == 0) oa[n] = a;
  if (ob){
    float c = wsum(x0 * vb[lane] + x1 * vb[lane + 64]);
    if (lane == 0) ob[n] = c;
  }
}

// ---------- C[M,128] = A[M,128] @ B[128,128], LDS-tiled, 8x4 regs/thread ----------
__global__ __launch_bounds__(256) void gemm128_k(const float* __restrict__ A,
    const float* __restrict__ Bm, float* __restrict__ C, int M)
{
  __shared__ float sB[32 * 128];
  __shared__ float sA[64 * 33];
  const int tid = threadIdx.x;
  const int n0 = blockIdx.x * 64;
  const int j4 = (tid & 31) * 4;
  const int rB = (tid >> 5) * 8;
  float acc[8][4];
  #pragma unroll
  for (int r = 0; r < 8; r++){ acc[r][0]=acc[r][1]=acc[r][2]=acc[r][3]=0.f; }
  for (int kc = 0; kc < 128; kc += 32){
    for (int t = tid; t < 4096; t += 256){
      int kk = t >> 7, j = t & 127;
      sB[kk * 128 + j] = Bm[(size_t)(kc + kk) * H + j];
    }
    for (int t = tid; t < 2048; t += 256){
      int n = t >> 5, kk = t & 31; int row = n0 + n;
      sA[n * 33 + kk] = (row < M) ? A[(size_t)row * H + kc + kk] : 0.f;
    }
    __syncthreads();
    #pragma unroll 8
    for (int kk = 0; kk < 32; kk++){
      float4 bv = *(const float4*)&sB[kk * 128 + j4];
      #pragma unroll
      for (int r = 0; r < 8; r++){
        float av = sA[(rB + r) * 33 + kk];
        acc[r][0] += av * bv.x; acc[r][1] += av * bv.y;
        acc[r][2] += av * bv.z; acc[r][3] += av * bv.w;
      }
    }
    __syncthreads();
  }
  #pragma unroll
  for (int r = 0; r < 8; r++){
    int row = n0 + rB + r;
    if (row < M){
      float4 o; o.x = acc[r][0]; o.y = acc[r][1]; o.z = acc[r][2]; o.w = acc[r][3];
      *(float4*)&C[(size_t)row * H + j4] = o;
    }
  }
}

// ---------- edge passes ----------
__global__ void amax_k(const int* __restrict__ src, const int* __restrict__ dst,
    const float* __restrict__ attr, const float* __restrict__ as_,
    const float* __restrict__ ad_, const float* __restrict__ coeff, int ci,
    float* __restrict__ alpha, unsigned* __restrict__ m, int NE)
{
  int e = blockIdx.x * 256 + threadIdx.x;
  if (e >= NE) return;
  float a = as_[src[e]] + ad_[dst[e]];
  if (attr) a += attr[e] * coeff[ci] + coeff[NL + ci];
  a = (a > 0.f) ? a : 0.2f * a;
  alpha[e] = a;
  atomicMax(&m[dst[e]], fenc(a));
}

__global__ void aexp_k(const int* __restrict__ dst, float* __restrict__ alpha,
    const unsigned* __restrict__ m, float* __restrict__ s, int NE)
{
  int e = blockIdx.x * 256 + threadIdx.x;
  if (e >= NE) return;
  int d = dst[e];
  float ex = expf(alpha[e] - fdec(m[d]));
  alpha[e] = ex;
  atomicAdd(&s[d], ex);
}

__global__ __launch_bounds__(256) void scat_k(const int* __restrict__ src,
    const int* __restrict__ dst, const float* __restrict__ alpha,
    const float* __restrict__ s, const float* __restrict__ X,
    float* __restrict__ out, int NE)
{
  int e = blockIdx.x * 2 + (threadIdx.x >> 7);
  if (e >= NE) return;
  int j = threadIdx.x & 127;
  float w = alpha[e] / s[dst[e]];
  atomicAdd(&out[(size_t)dst[e] * H + j], X[(size_t)src[e] * H + j] * w);
}

// ---------- fused FFN: h += relu(xn@W1+b1)@W2 + b2 ; chunked over DFF ----------
__global__ __launch_bounds__(256) void ffn_k(const float* __restrict__ xn,
    float* __restrict__ h, const float* __restrict__ W1, const float* __restrict__ b1,
    const float* __restrict__ W2, const float* __restrict__ b2, int M)
{
  __shared__ float sX[64 * 132];   // xn tile, padded
  __shared__ float sW1[32 * 132];  // W1 chunk, transposed [jj][k]
  __shared__ float sW2[32 * 128];  // W2 chunk [jj][jo]
  __shared__ float sT[64 * 33];    // relu'd intermediate [n][jj]
  const int tid = threadIdx.x;
  const int n0 = blockIdx.x * 64;
  for (int t = tid; t < 8192; t += 256){
    int n = t >> 7, j = t & 127; int row = n0 + n;
    sX[n * 132 + j] = (row < M) ? xn[(size_t)row * H + j] : 0.f;
  }
  float acc[8][4];
  #pragma unroll
  for (int r = 0; r < 8; r++){ acc[r][0]=acc[r][1]=acc[r][2]=acc[r][3]=0.f; }
  const int joB = (tid & 31) * 4;
  const int nB  = (tid >> 5) * 8;
  const int jg = tid & 7, ng = tid >> 3;
  __syncthreads();
  for (int d0 = 0; d0 < DFF; d0 += 32){
    for (int t = tid; t < 4096; t += 256){
      int k = t >> 5, jj = t & 31;
      sW1[jj * 132 + k] = W1[(size_t)k * DFF + d0 + jj];
    }
    for (int t = tid; t < 4096; t += 256){
      sW2[t] = W2[(size_t)d0 * H + t];
    }
    __syncthreads();
    float ta[2][4];
    #pragma unroll
    for (int r = 0; r < 2; r++) for (int c = 0; c < 4; c++) ta[r][c] = 0.f;
    #pragma unroll 4
    for (int k = 0; k < 128; k += 4){
      float4 xa = *(const float4*)&sX[(2 * ng) * 132 + k];
      float4 xb = *(const float4*)&sX[(2 * ng + 1) * 132 + k];
      #pragma unroll
      for (int c = 0; c < 4; c++){
        float4 w = *(const float4*)&sW1[(4 * jg + c) * 132 + k];
        ta[0][c] += xa.x * w.x + xa.y * w.y + xa.z * w.z + xa.w * w.w;
        ta[1][c] += xb.x * w.x + xb.y * w.y + xb.z * w.z + xb.w * w.w;
      }
    }
    #pragma unroll
    for (int r = 0; r < 2; r++)
      #pragma unroll
      for (int c = 0; c < 4; c++){
        float v = ta[r][c] + b1[d0 + 4 * jg + c];
        sT[(2 * ng + r) * 33 + 4 * jg + c] = fmaxf(v, 0.f);
      }
    __syncthreads();
    #pragma unroll 8
    for (int jj = 0; jj < 32; jj++){
      float4 w = *(const float4*)&sW2[jj * 128 + joB];
      #pragma unroll
      for (int r = 0; r < 8; r++){
        float tv = sT[(nB + r) * 33 + jj];
        acc[r][0] += tv * w.x; acc[r][1] += tv * w.y;
        acc[r][2] += tv * w.z; acc[r][3] += tv * w.w;
      }
    }
    __syncthreads();
  }
  #pragma unroll
  for (int r = 0; r < 8; r++){
    int row = n0 + nB + r;
    if (row < M){
      float4 hv = *(float4*)&h[(size_t)row * H + joB];
      hv.x += acc[r][0] + b2[joB + 0];
      hv.y += acc[r][1] + b2[joB + 1];
      hv.z += acc[r][2] + b2[joB + 2];
      hv.w += acc[r][3] + b2[joB + 3];
      *(float4*)&h[(size_t)row * H + joB] = hv;
    }
  }
}

// ---------- final well MLP ----------
__global__ __launch_bounds__(128) void mlp_k(const float* __restrict__ hwell,
    const float* __restrict__ wb, const float* __restrict__ mW1,
    const float* __restrict__ mb1, const float* __restrict__ mW2,
    const float* __restrict__ mb2, float* __restrict__ out)
{
  __shared__ float sH[128], sT[128];
  int n = blockIdx.x, j = threadIdx.x;
  sH[j] = hwell[(size_t)n * H + j] + wb[j];
  __syncthreads();
  float a = mb1[j];
  for (int k = 0; k < 128; k++) a += sH[k] * mW1[k * 128 + j];
  sT[j] = fmaxf(a, 0.f);
  __syncthreads();
  if (j < 75){
    float o = mb2[j];
    for (int k = 0; k < 128; k++) o += sT[k] * mW2[k * 75 + j];
    out[(size_t)n * 75 + j] = o;
  }
}

extern "C" void kernel_launch(void* const* d_in, const int* in_sizes, int n_in,
                              void* d_out, int out_size, void* d_ws, size_t ws_size,
                              hipStream_t stream)
{
  (void)in_sizes; (void)n_in; (void)out_size; (void)ws_size;
  const float* cell_x = (const float*)d_in[0];
  const float* well_x = (const float*)d_in[1];
  const int*   eidx   = (const int*)d_in[2];
  const float* eattr  = (const float*)d_in[3];
  const int*   wsrc   = (const int*)d_in[4];
  const int*   wdst   = (const int*)d_in[5];
  const float* W_cell = (const float*)d_in[6];
  const float* b_cell = (const float*)d_in[7];
  const float* W_well = (const float*)d_in[8];
  const float* b_well = (const float*)d_in[9];
  const float* W_ee   = (const float*)d_in[10];
  const float* b_ee   = (const float*)d_in[11];
  const float* gW     = (const float*)d_in[12];
  const float* gas    = (const float*)d_in[13];
  const float* gad    = (const float*)d_in[14];
  const float* gae    = (const float*)d_in[15];
  const float* gWe    = (const float*)d_in[16];
  const float* gb     = (const float*)d_in[17];
  const float* n1g    = (const float*)d_in[18];
  const float* n1b    = (const float*)d_in[19];
  const float* fW1    = (const float*)d_in[20];
  const float* fb1    = (const float*)d_in[21];
  const float* fW2    = (const float*)d_in[22];
  const float* fb2    = (const float*)d_in[23];
  const float* n2g    = (const float*)d_in[24];
  const float* n2b    = (const float*)d_in[25];
  const float* wW     = (const float*)d_in[26];
  const float* was    = (const float*)d_in[27];
  const float* wad    = (const float*)d_in[28];
  const float* wb     = (const float*)d_in[29];
  const float* mW1    = (const float*)d_in[30];
  const float* mb1    = (const float*)d_in[31];
  const float* mW2    = (const float*)d_in[32];
  const float* mb2    = (const float*)d_in[33];

  const int* src = eidx;
  const int* dst = eidx + NE_CC;

  float* ws = (float*)d_ws;
  size_t o = 0;
  float* h     = ws + o; o += (size_t)NC * H;
  float* xn    = ws + o; o += (size_t)NC * H;
  float* hs    = ws + o; o += (size_t)NC * H;
  float* as_   = ws + o; o += NC;
  float* ad_   = ws + o; o += NC;
  unsigned* mx = (unsigned*)(ws + o); o += NC;
  float* ssum  = ws + o; o += NC;
  float* alpha = ws + o; o += NE_CC;
  float* hw    = ws + o; o += (size_t)NW * H;
  float* hwp   = ws + o; o += (size_t)NW * H;
  float* hwell = ws + o; o += (size_t)NW * H;
  float* coeff = ws + o; o += 8;

  embed_k<32><<<2048, 256, 0, stream>>>(cell_x, W_cell, b_cell, h, NC);
  embed_k<16><<<250, 256, 0, stream>>>(well_x, W_well, b_well, hw, NW);
  coeff_k<<<1, 128, 0, stream>>>(gWe, gae, W_ee, b_ee, coeff);

  const int lnBlocks = (NC + 3) / 4;
  const int gemmBlocks = (NC + 63) / 64;
  const int eBlocks = (NE_CC + 255) / 256;

  for (int i = 0; i < NL; i++){
    ln_k<<<lnBlocks, 256, 0, stream>>>(h, nullptr, n1g + i * H, n1b + i * H, nullptr, xn, NC);
    gemm128_k<<<gemmBlocks, 256, 0, stream>>>(xn, gW + (size_t)i * H * H, hs, NC);
    dot2_k<<<lnBlocks, 256, 0, stream>>>(hs, gas + i * H, gad + i * H, as_, ad_, NC);
    hipMemsetAsync(mx, 0, NC * sizeof(unsigned), stream);
    hipMemsetAsync(ssum, 0, NC * sizeof(float), stream);
    amax_k<<<eBlocks, 256, 0, stream>>>(src, dst, eattr, as_, ad_, coeff, i, alpha, mx, NE_CC);
    aexp_k<<<eBlocks, 256, 0, stream>>>(dst, alpha, mx, ssum, NE_CC);
    scat_k<<<(NE_CC + 1) / 2, 256, 0, stream>>>(src, dst, alpha, ssum, hs, h, NE_CC);
    ln_k<<<lnBlocks, 256, 0, stream>>>(h, h, n2g + i * H, n2b + i * H, gb + i * H, xn, NC);
    ffn_k<<<gemmBlocks, 256, 0, stream>>>(xn, h,
        fW1 + (size_t)i * H * DFF, fb1 + (size_t)i * DFF,
        fW2 + (size_t)i * DFF * H, fb2 + (size_t)i * H, NC);
  }

  // cell -> well bipartite GAT
  gemm128_k<<<gemmBlocks, 256, 0, stream>>>(h, wW, hs, NC);          // hc
  gemm128_k<<<(NW + 63) / 64, 256, 0, stream>>>(hw, wW, hwp, NW);    // hwp
  dot2_k<<<lnBlocks, 256, 0, stream>>>(hs, was, was, as_, nullptr, NC);
  dot2_k<<<(NW + 3) / 4, 256, 0, stream>>>(hwp, wad, wad, ad_, nullptr, NW);
  hipMemsetAsync(mx, 0, NW * sizeof(unsigned), stream);
  hipMemsetAsync(ssum, 0, NW * sizeof(float), stream);
  hipMemsetAsync(hwell, 0, (size_t)NW * H * sizeof(float), stream);
  const int ewBlocks = (NE_CW + 255) / 256;
  amax_k<<<ewBlocks, 256, 0, stream>>>(wsrc, wdst, nullptr, as_, ad_, nullptr, 0, alpha, mx, NE_CW);
  aexp_k<<<ewBlocks, 256, 0, stream>>>(wdst, alpha, mx, ssum, NE_CW);
  scat_k<<<(NE_CW + 1) / 2, 256, 0, stream>>>(wsrc, wdst, alpha, ssum, hs, hwell, NE_CW);
  mlp_k<<<NW, 128, 0, stream>>>(hwell, wb, mW1, mb1, mW2, mb2, (float*)d_out);
}

// Round 2
// 1630.750 us; speedup vs baseline: 2.1003x; 2.1003x over previous
//
#include <hip/hip_runtime.h>
#include <hip/hip_bf16.h>

#define NC 100000
#define NW 500
#define NE_CC 600000
#define NE_CW 25000
#define H 128
#define NL 3
#define DFF 512
#define DC 64

typedef __bf16 bf16x8 __attribute__((ext_vector_type(8)));
typedef float f32x4 __attribute__((ext_vector_type(4)));
#define MFMA16(a,b,c) __builtin_amdgcn_mfma_f32_16x16x32_bf16(a,b,c,0,0,0)

__device__ __forceinline__ float wsum(float v){
  #pragma unroll
  for (int o = 32; o; o >>= 1) v += __shfl_xor(v, o, 64);
  return v;
}
__device__ __forceinline__ unsigned fenc(float f){
  unsigned u = __float_as_uint(f);
  return (u & 0x80000000u) ? ~u : (u | 0x80000000u);
}
__device__ __forceinline__ float fdec(unsigned u){
  u = (u & 0x80000000u) ? (u ^ 0x80000000u) : ~u;
  return __uint_as_float(u);
}

// ---------- weight prep: out[l][n][k] = bf16(in[l][k][n]) ----------
__global__ void prep_T_k(const float* __restrict__ in, __hip_bfloat16* __restrict__ out,
                         int K, int N, int nmat)
{
  size_t tot = (size_t)nmat * K * N;
  for (size_t i = blockIdx.x * 256 + threadIdx.x; i < tot; i += (size_t)gridDim.x * 256){
    size_t l = i / ((size_t)K * N);
    size_t rem = i - l * (size_t)K * N;
    int n = (int)(rem / K), k = (int)(rem % K);
    out[i] = __float2bfloat16(in[l * (size_t)K * N + (size_t)k * N + n]);
  }
}

// ---------- embeddings: h = x @ W + b ----------
template<int K>
__global__ __launch_bounds__(256) void embed_k(const float* __restrict__ x,
    const float* __restrict__ W, const float* __restrict__ b,
    float* __restrict__ h, int M)
{
  __shared__ float sW[K * 128];
  for (int t = threadIdx.x; t < K * 128; t += 256) sW[t] = W[t];
  __syncthreads();
  int j = threadIdx.x & 127, half = threadIdx.x >> 7;
  float bj = b[j];
  for (int n = blockIdx.x * 2 + half; n < M; n += gridDim.x * 2){
    const float* xr = x + (size_t)n * K;
    float acc = bj;
    #pragma unroll
    for (int k = 0; k < K; k++) acc += xr[k] * sW[k * 128 + j];
    h[(size_t)n * H + j] = acc;
  }
}

// ---------- per-layer scalar edge coefficients ----------
__global__ void coeff_k(const float* __restrict__ gWe, const float* __restrict__ gae,
    const float* __restrict__ Wee, const float* __restrict__ bee, float* __restrict__ coeff)
{
  __shared__ float red[4];
  int t = threadIdx.x;  // 0..127
  for (int i = 0; i < NL; i++){
    const float* Wr = gWe + ((size_t)i * H + t) * H;
    const float* ga = gae + (size_t)i * H;
    float w = 0.f;
    for (int k = 0; k < H; k++) w += Wr[k] * ga[k];
    float pc = Wee[t] * w, pd = bee[t] * w;
    pc = wsum(pc); pd = wsum(pd);
    if ((t & 63) == 0){ red[(t >> 6) * 2 + 0] = pc; red[(t >> 6) * 2 + 1] = pd; }
    __syncthreads();
    if (t == 0){ coeff[i] = red[0] + red[2]; coeff[NL + i] = red[1] + red[3]; }
    __syncthreads();
  }
}

// ---------- LayerNorm -> bf16 xn; optional pre-add + fp32 writeback ----------
__global__ __launch_bounds__(256) void ln_k(const float* __restrict__ hin,
    float* __restrict__ hout, const float* __restrict__ g, const float* __restrict__ b,
    const float* __restrict__ addv, __hip_bfloat16* __restrict__ xn, int M)
{
  int lane = threadIdx.x & 63, wid = threadIdx.x >> 6;
  int n = blockIdx.x * 4 + wid;
  if (n >= M) return;
  const float* row = hin + (size_t)n * H;
  float x0 = row[lane], x1 = row[lane + 64];
  if (addv){ x0 += addv[lane]; x1 += addv[lane + 64]; }
  float mu = wsum(x0 + x1) * (1.f / H);
  float d0 = x0 - mu, d1 = x1 - mu;
  float var = wsum(d0 * d0 + d1 * d1) * (1.f / H);
  float rs = rsqrtf(var + 1e-5f);
  if (hout){ hout[(size_t)n * H + lane] = x0; hout[(size_t)n * H + lane + 64] = x1; }
  xn[(size_t)n * H + lane]      = __float2bfloat16(d0 * rs * g[lane]      + b[lane]);
  xn[(size_t)n * H + lane + 64] = __float2bfloat16(d1 * rs * g[lane + 64] + b[lane + 64]);
}

// ---------- dual dot products per node ----------
__global__ __launch_bounds__(256) void dot2_k(const float* __restrict__ X,
    const float* __restrict__ va, const float* __restrict__ vb,
    float* __restrict__ oa, float* __restrict__ ob, int M)
{
  int lane = threadIdx.x & 63, wid = threadIdx.x >> 6;
  int n = blockIdx.x * 4 + wid;
  if (n >= M) return;
  const float* row = X + (size_t)n * H;
  float x0 = row[lane], x1 = row[lane + 64];
  float a = wsum(x0 * va[lane] + x1 * va[lane + 64]);
  if (lane == 0) oa[n] = a;
  if (ob){
    float c = wsum(x0 * vb[lane] + x1 * vb[lane + 64]);
    if (lane == 0) ob[n] = c;
  }
}

// ---------- MFMA GEMM: C[M,128] f32 = A(bf16)[M,128] @ WT(bf16)[128n][128k] ----------
__global__ __launch_bounds__(512, 4) void gemm_mfma_k(
    const __hip_bfloat16* __restrict__ A, const __hip_bfloat16* __restrict__ WT,
    float* __restrict__ C, int M)
{
  __shared__ __hip_bfloat16 sX[128 * 128];
  __shared__ __hip_bfloat16 sW[128 * 128];
  const int tid = threadIdx.x;
  const int lane = tid & 63, w = tid >> 6;
  const int n0 = blockIdx.x * 128;
  const int rw = w * 16;
  const int lr = lane & 15, lk = lane >> 4;

  for (int c = tid; c < 2048; c += 512){
    int r = c >> 4, s = c & 15;
    int row = n0 + r;
    uint4 v = make_uint4(0u, 0u, 0u, 0u);
    if (row < M) v = *(const uint4*)(A + (size_t)row * 128 + s * 8);
    *(uint4*)((char*)sX + r * 256 + ((s * 16) ^ ((r & 7) << 4))) = v;
  }
  for (int c = tid; c < 2048; c += 512){
    int r = c >> 4, s = c & 15;
    uint4 v = *(const uint4*)(WT + (size_t)r * 128 + s * 8);
    *(uint4*)((char*)sW + r * 256 + ((s * 16) ^ ((r & 7) << 4))) = v;
  }
  __syncthreads();

  f32x4 acc[8];
  #pragma unroll
  for (int i = 0; i < 8; i++) acc[i] = (f32x4){0.f, 0.f, 0.f, 0.f};
  #pragma unroll
  for (int ks = 0; ks < 4; ks++){
    int arow = rw + lr;
    int ak = ks * 32 + lk * 8;
    bf16x8 a = *(const bf16x8*)((const char*)sX + arow * 256 + ((ak * 2) ^ ((arow & 7) << 4)));
    #pragma unroll
    for (int nt = 0; nt < 8; nt++){
      int brow = nt * 16 + lr;
      bf16x8 b = *(const bf16x8*)((const char*)sW + brow * 256 + ((ak * 2) ^ ((brow & 7) << 4)));
      acc[nt] = MFMA16(a, b, acc[nt]);
    }
  }
  #pragma unroll
  for (int nt = 0; nt < 8; nt++){
    int col = nt * 16 + lr;
    #pragma unroll
    for (int r = 0; r < 4; r++){
      int row = n0 + rw + lk * 4 + r;
      if (row < M) C[(size_t)row * 128 + col] = acc[nt][r];
    }
  }
}

// ---------- MFMA fused FFN: h += relu(xn@W1+b1)@W2 + b2 ----------
__global__ __launch_bounds__(512, 4) void ffn_mfma_k(
    const __hip_bfloat16* __restrict__ xn, float* __restrict__ h,
    const __hip_bfloat16* __restrict__ W1T, const float* __restrict__ b1,
    const __hip_bfloat16* __restrict__ W2T, const float* __restrict__ b2,
    __hip_bfloat16* __restrict__ hbf, int writeHbf, int M)
{
  __shared__ __hip_bfloat16 sX[128 * 128];   // 32 KB
  __shared__ __hip_bfloat16 sW1[DC * 128];   // 16 KB [n_local][k]
  __shared__ __hip_bfloat16 sW2[128 * DC];   // 16 KB [n][k_local]
  __shared__ __hip_bfloat16 sT[128 * DC];    // 16 KB [row][k_local]
  const int tid = threadIdx.x;
  const int lane = tid & 63, w = tid >> 6;
  const int n0 = blockIdx.x * 128;
  const int rw = w * 16;
  const int lr = lane & 15, lk = lane >> 4;

  // stage X tile (swizzled)
  for (int c = tid; c < 2048; c += 512){
    int r = c >> 4, s = c & 15;
    int row = n0 + r;
    uint4 v = make_uint4(0u, 0u, 0u, 0u);
    if (row < M) v = *(const uint4*)(xn + (size_t)row * 128 + s * 8);
    *(uint4*)((char*)sX + r * 256 + ((s * 16) ^ ((r & 7) << 4))) = v;
  }

  f32x4 acc2[8];
  #pragma unroll
  for (int i = 0; i < 8; i++) acc2[i] = (f32x4){0.f, 0.f, 0.f, 0.f};

  for (int ch = 0; ch < DFF / DC; ch++){
    __syncthreads();  // covers sX on first iter; protects sW1/sW2 restage after
    // stage W1 chunk: DC rows x 256B
    for (int c = tid; c < 1024; c += 512){
      int r = c >> 4, s = c & 15;
      uint4 v = *(const uint4*)(W1T + (size_t)(ch * DC + r) * 128 + s * 8);
      *(uint4*)((char*)sW1 + r * 256 + ((s * 16) ^ ((r & 7) << 4))) = v;
    }
    // stage W2 chunk: 128 rows x 128B
    for (int c = tid; c < 1024; c += 512){
      int r = c >> 3, s = c & 7;
      uint4 v = *(const uint4*)(W2T + (size_t)r * DFF + ch * DC + s * 8);
      *(uint4*)((char*)sW2 + r * 128 + ((s * 16) ^ ((r & 7) << 4))) = v;
    }
    __syncthreads();

    // GEMM1: T[rw..rw+15][0..DC) = X @ W1c
    f32x4 acc1[4];
    #pragma unroll
    for (int i = 0; i < 4; i++) acc1[i] = (f32x4){0.f, 0.f, 0.f, 0.f};
    #pragma unroll
    for (int ks = 0; ks < 4; ks++){
      int arow = rw + lr;
      int ak = ks * 32 + lk * 8;
      bf16x8 a = *(const bf16x8*)((const char*)sX + arow * 256 + ((ak * 2) ^ ((arow & 7) << 4)));
      #pragma unroll
      for (int nt = 0; nt < 4; nt++){
        int brow = nt * 16 + lr;
        bf16x8 b = *(const bf16x8*)((const char*)sW1 + brow * 256 + ((ak * 2) ^ ((brow & 7) << 4)));
        acc1[nt] = MFMA16(a, b, acc1[nt]);
      }
    }
    // bias + relu -> bf16 -> sT (wave-local rows; no cross-wave barrier needed)
    #pragma unroll
    for (int nt = 0; nt < 4; nt++){
      int col = nt * 16 + lr;
      float bb = b1[ch * DC + col];
      #pragma unroll
      for (int r = 0; r < 4; r++){
        int row = rw + lk * 4 + r;
        float v = fmaxf(acc1[nt][r] + bb, 0.f);
        *(__hip_bfloat16*)((char*)sT + row * 128 + ((col * 2) ^ ((row & 7) << 4))) =
            __float2bfloat16(v);
      }
    }
    asm volatile("s_waitcnt lgkmcnt(0)" ::: "memory");

    // GEMM2: acc2 += T @ W2c
    #pragma unroll
    for (int ks = 0; ks < 2; ks++){
      int arow = rw + lr;
      int ak = ks * 32 + lk * 8;
      bf16x8 a = *(const bf16x8*)((const char*)sT + arow * 128 + ((ak * 2) ^ ((arow & 7) << 4)));
      #pragma unroll
      for (int nt = 0; nt < 8; nt++){
        int brow = nt * 16 + lr;
        bf16x8 b = *(const bf16x8*)((const char*)sW2 + brow * 128 + ((ak * 2) ^ ((brow & 7) << 4)));
        acc2[nt] = MFMA16(a, b, acc2[nt]);
      }
    }
  }

  // epilogue: h += acc2 + b2
  #pragma unroll
  for (int nt = 0; nt < 8; nt++){
    int col = nt * 16 + lr;
    float bb = b2[col];
    #pragma unroll
    for (int r = 0; r < 4; r++){
      int row = n0 + rw + lk * 4 + r;
      if (row < M){
        float v = h[(size_t)row * 128 + col] + acc2[nt][r] + bb;
        h[(size_t)row * 128 + col] = v;
        if (writeHbf) hbf[(size_t)row * 128 + col] = __float2bfloat16(v);
      }
    }
  }
}

// ---------- fp32 GEMM (kept for tiny well matmul) ----------
__global__ __launch_bounds__(256) void gemm128_k(const float* __restrict__ A,
    const float* __restrict__ Bm, float* __restrict__ C, int M)
{
  __shared__ float sB[32 * 128];
  __shared__ float sA[64 * 33];
  const int tid = threadIdx.x;
  const int n0 = blockIdx.x * 64;
  const int j4 = (tid & 31) * 4;
  const int rB = (tid >> 5) * 8;
  float acc[8][4];
  #pragma unroll
  for (int r = 0; r < 8; r++){ acc[r][0]=acc[r][1]=acc[r][2]=acc[r][3]=0.f; }
  for (int kc = 0; kc < 128; kc += 32){
    for (int t = tid; t < 4096; t += 256){
      int kk = t >> 7, j = t & 127;
      sB[kk * 128 + j] = Bm[(size_t)(kc + kk) * H + j];
    }
    for (int t = tid; t < 2048; t += 256){
      int n = t >> 5, kk = t & 31; int row = n0 + n;
      sA[n * 33 + kk] = (row < M) ? A[(size_t)row * H + kc + kk] : 0.f;
    }
    __syncthreads();
    #pragma unroll 8
    for (int kk = 0; kk < 32; kk++){
      float4 bv = *(const float4*)&sB[kk * 128 + j4];
      #pragma unroll
      for (int r = 0; r < 8; r++){
        float av = sA[(rB + r) * 33 + kk];
        acc[r][0] += av * bv.x; acc[r][1] += av * bv.y;
        acc[r][2] += av * bv.z; acc[r][3] += av * bv.w;
      }
    }
    __syncthreads();
  }
  #pragma unroll
  for (int r = 0; r < 8; r++){
    int row = n0 + rB + r;
    if (row < M){
      float4 o; o.x = acc[r][0]; o.y = acc[r][1]; o.z = acc[r][2]; o.w = acc[r][3];
      *(float4*)&C[(size_t)row * H + j4] = o;
    }
  }
}

// ---------- edge passes ----------
__global__ void amax_k(const int* __restrict__ src, const int* __restrict__ dst,
    const float* __restrict__ attr, const float* __restrict__ as_,
    const float* __restrict__ ad_, const float* __restrict__ coeff, int ci,
    float* __restrict__ alpha, unsigned* __restrict__ m, int NE)
{
  int e = blockIdx.x * 256 + threadIdx.x;
  if (e >= NE) return;
  float a = as_[src[e]] + ad_[dst[e]];
  if (attr) a += attr[e] * coeff[ci] + coeff[NL + ci];
  a = (a > 0.f) ? a : 0.2f * a;
  alpha[e] = a;
  atomicMax(&m[dst[e]], fenc(a));
}

__global__ void aexp_k(const int* __restrict__ dst, float* __restrict__ alpha,
    const unsigned* __restrict__ m, float* __restrict__ s, int NE)
{
  int e = blockIdx.x * 256 + threadIdx.x;
  if (e >= NE) return;
  int d = dst[e];
  float ex = expf(alpha[e] - fdec(m[d]));
  alpha[e] = ex;
  atomicAdd(&s[d], ex);
}

__global__ __launch_bounds__(256) void scat_k(const int* __restrict__ src,
    const int* __restrict__ dst, const float* __restrict__ alpha,
    const float* __restrict__ s, const float* __restrict__ X,
    float* __restrict__ out, int NE)
{
  int e = blockIdx.x * 2 + (threadIdx.x >> 7);
  if (e >= NE) return;
  int j = threadIdx.x & 127;
  float w = alpha[e] / s[dst[e]];
  atomicAdd(&out[(size_t)dst[e] * H + j], X[(size_t)src[e] * H + j] * w);
}

// ---------- final well MLP ----------
__global__ __launch_bounds__(128) void mlp_k(const float* __restrict__ hwell,
    const float* __restrict__ wb, const float* __restrict__ mW1,
    const float* __restrict__ mb1, const float* __restrict__ mW2,
    const float* __restrict__ mb2, float* __restrict__ out)
{
  __shared__ float sH[128], sT[128];
  int n = blockIdx.x, j = threadIdx.x;
  sH[j] = hwell[(size_t)n * H + j] + wb[j];
  __syncthreads();
  float a = mb1[j];
  for (int k = 0; k < 128; k++) a += sH[k] * mW1[k * 128 + j];
  sT[j] = fmaxf(a, 0.f);
  __syncthreads();
  if (j < 75){
    float o = mb2[j];
    for (int k = 0; k < 128; k++) o += sT[k] * mW2[k * 75 + j];
    out[(size_t)n * 75 + j] = o;
  }
}

extern "C" void kernel_launch(void* const* d_in, const int* in_sizes, int n_in,
                              void* d_out, int out_size, void* d_ws, size_t ws_size,
                              hipStream_t stream)
{
  (void)in_sizes; (void)n_in; (void)out_size; (void)ws_size;
  const float* cell_x = (const float*)d_in[0];
  const float* well_x = (const float*)d_in[1];
  const int*   eidx   = (const int*)d_in[2];
  const float* eattr  = (const float*)d_in[3];
  const int*   wsrc   = (const int*)d_in[4];
  const int*   wdst   = (const int*)d_in[5];
  const float* W_cell = (const float*)d_in[6];
  const float* b_cell = (const float*)d_in[7];
  const float* W_well = (const float*)d_in[8];
  const float* b_well = (const float*)d_in[9];
  const float* W_ee   = (const float*)d_in[10];
  const float* b_ee   = (const float*)d_in[11];
  const float* gW     = (const float*)d_in[12];
  const float* gas    = (const float*)d_in[13];
  const float* gad    = (const float*)d_in[14];
  const float* gae    = (const float*)d_in[15];
  const float* gWe    = (const float*)d_in[16];
  const float* gb     = (const float*)d_in[17];
  const float* n1g    = (const float*)d_in[18];
  const float* n1b    = (const float*)d_in[19];
  const float* fW1    = (const float*)d_in[20];
  const float* fb1    = (const float*)d_in[21];
  const float* fW2    = (const float*)d_in[22];
  const float* fb2    = (const float*)d_in[23];
  const float* n2g    = (const float*)d_in[24];
  const float* n2b    = (const float*)d_in[25];
  const float* wW     = (const float*)d_in[26];
  const float* was    = (const float*)d_in[27];
  const float* wad    = (const float*)d_in[28];
  const float* wb     = (const float*)d_in[29];
  const float* mW1    = (const float*)d_in[30];
  const float* mb1    = (const float*)d_in[31];
  const float* mW2    = (const float*)d_in[32];
  const float* mb2    = (const float*)d_in[33];

  const int* src = eidx;
  const int* dst = eidx + NE_CC;

  char* wsb = (char*)d_ws;
  size_t off = 0;
  auto alloc = [&](size_t bytes) -> void* {
    void* p = wsb + off; off += (bytes + 255) & ~(size_t)255; return p;
  };
  float* h      = (float*)alloc((size_t)NC * H * 4);
  float* hs     = (float*)alloc((size_t)NC * H * 4);
  __hip_bfloat16* xnbf = (__hip_bfloat16*)alloc((size_t)NC * H * 2);
  __hip_bfloat16* hbf  = xnbf;  // alias: xn dead when hbf written (last FFN)
  float* as_    = (float*)alloc((size_t)NC * 4);
  float* ad_    = (float*)alloc((size_t)NC * 4);
  unsigned* mx  = (unsigned*)alloc((size_t)NC * 4);
  float* ssum   = (float*)alloc((size_t)NC * 4);
  float* alpha  = (float*)alloc((size_t)NE_CC * 4);
  float* hw     = (float*)alloc((size_t)NW * H * 4);
  float* hwp    = (float*)alloc((size_t)NW * H * 4);
  float* hwell  = (float*)alloc((size_t)NW * H * 4);
  float* coeff  = (float*)alloc(64);
  __hip_bfloat16* gWT = (__hip_bfloat16*)alloc((size_t)NL * H * H * 2);
  __hip_bfloat16* W1T = (__hip_bfloat16*)alloc((size_t)NL * DFF * H * 2);
  __hip_bfloat16* W2T = (__hip_bfloat16*)alloc((size_t)NL * H * DFF * 2);
  __hip_bfloat16* wWT = (__hip_bfloat16*)alloc((size_t)H * H * 2);

  // weight prep (bf16 + transpose to [n][k])
  prep_T_k<<<192, 256, 0, stream>>>(gW, gWT, 128, 128, NL);
  prep_T_k<<<768, 256, 0, stream>>>(fW1, W1T, 128, 512, NL);
  prep_T_k<<<768, 256, 0, stream>>>(fW2, W2T, 512, 128, NL);
  prep_T_k<<<64, 256, 0, stream>>>(wW, wWT, 128, 128, 1);

  embed_k<32><<<2048, 256, 0, stream>>>(cell_x, W_cell, b_cell, h, NC);
  embed_k<16><<<250, 256, 0, stream>>>(well_x, W_well, b_well, hw, NW);
  coeff_k<<<1, 128, 0, stream>>>(gWe, gae, W_ee, b_ee, coeff);

  const int lnBlocks = (NC + 3) / 4;
  const int mfmaBlocks = (NC + 127) / 128;
  const int eBlocks = (NE_CC + 255) / 256;

  for (int i = 0; i < NL; i++){
    ln_k<<<lnBlocks, 256, 0, stream>>>(h, nullptr, n1g + i * H, n1b + i * H, nullptr, xnbf, NC);
    gemm_mfma_k<<<mfmaBlocks, 512, 0, stream>>>(xnbf, gWT + (size_t)i * H * H, hs, NC);
    dot2_k<<<lnBlocks, 256, 0, stream>>>(hs, gas + i * H, gad + i * H, as_, ad_, NC);
    hipMemsetAsync(mx, 0, NC * sizeof(unsigned), stream);
    hipMemsetAsync(ssum, 0, NC * sizeof(float), stream);
    amax_k<<<eBlocks, 256, 0, stream>>>(src, dst, eattr, as_, ad_, coeff, i, alpha, mx, NE_CC);
    aexp_k<<<eBlocks, 256, 0, stream>>>(dst, alpha, mx, ssum, NE_CC);
    scat_k<<<(NE_CC + 1) / 2, 256, 0, stream>>>(src, dst, alpha, ssum, hs, h, NE_CC);
    ln_k<<<lnBlocks, 256, 0, stream>>>(h, h, n2g + i * H, n2b + i * H, gb + i * H, xnbf, NC);
    ffn_mfma_k<<<mfmaBlocks, 512, 0, stream>>>(xnbf, h,
        W1T + (size_t)i * DFF * H, fb1 + (size_t)i * DFF,
        W2T + (size_t)i * H * DFF, fb2 + (size_t)i * H,
        hbf, (i == NL - 1) ? 1 : 0, NC);
  }

  // cell -> well bipartite GAT
  gemm_mfma_k<<<mfmaBlocks, 512, 0, stream>>>(hbf, wWT, hs, NC);     // hc
  gemm128_k<<<(NW + 63) / 64, 256, 0, stream>>>(hw, wW, hwp, NW);    // hwp
  dot2_k<<<lnBlocks, 256, 0, stream>>>(hs, was, was, as_, nullptr, NC);
  dot2_k<<<(NW + 3) / 4, 256, 0, stream>>>(hwp, wad, wad, ad_, nullptr, NW);
  hipMemsetAsync(mx, 0, NW * sizeof(unsigned), stream);
  hipMemsetAsync(ssum, 0, NW * sizeof(float), stream);
  hipMemsetAsync(hwell, 0, (size_t)NW * H * sizeof(float), stream);
  const int ewBlocks = (NE_CW + 255) / 256;
  amax_k<<<ewBlocks, 256, 0, stream>>>(wsrc, wdst, nullptr, as_, ad_, nullptr, 0, alpha, mx, NE_CW);
  aexp_k<<<ewBlocks, 256, 0, stream>>>(wdst, alpha, mx, ssum, NE_CW);
  scat_k<<<(NE_CW + 1) / 2, 256, 0, stream>>>(wsrc, wdst, alpha, ssum, hs, hwell, NE_CW);
  mlp_k<<<NW, 128, 0, stream>>>(hwell, wb, mW1, mb1, mW2, mb2, (float*)d_out);
}

// Round 3
// 817.610 us; speedup vs baseline: 4.1891x; 1.9945x over previous
//
#include <hip/hip_runtime.h>
#include <hip/hip_bf16.h>

#define NC 100000
#define NW 500
#define NE_CC 600000
#define NE_CW 25000
#define H 128
#define NL 3
#define DFF 512
#define DC 64

typedef __bf16 bf16x8 __attribute__((ext_vector_type(8)));
typedef float f32x4 __attribute__((ext_vector_type(4)));
#define MFMA16(a,b,c) __builtin_amdgcn_mfma_f32_16x16x32_bf16(a,b,c,0,0,0)

__device__ __forceinline__ float wsum(float v){
  #pragma unroll
  for (int o = 32; o; o >>= 1) v += __shfl_xor(v, o, 64);
  return v;
}
__device__ __forceinline__ float wmax(float v){
  #pragma unroll
  for (int o = 32; o; o >>= 1) v = fmaxf(v, __shfl_xor(v, o, 64));
  return v;
}

// ---------- weight prep: out[l][n][k] = bf16(in[l][k][n]) ----------
__global__ void prep_T_k(const float* __restrict__ in, __hip_bfloat16* __restrict__ out,
                         int K, int N, int nmat)
{
  size_t tot = (size_t)nmat * K * N;
  for (size_t i = blockIdx.x * 256 + threadIdx.x; i < tot; i += (size_t)gridDim.x * 256){
    size_t l = i / ((size_t)K * N);
    size_t rem = i - l * (size_t)K * N;
    int n = (int)(rem / K), k = (int)(rem % K);
    out[i] = __float2bfloat16(in[l * (size_t)K * N + (size_t)k * N + n]);
  }
}

// ---------- embeddings ----------
template<int K>
__global__ __launch_bounds__(256) void embed_k(const float* __restrict__ x,
    const float* __restrict__ W, const float* __restrict__ b,
    float* __restrict__ h, int M)
{
  __shared__ float sW[K * 128];
  for (int t = threadIdx.x; t < K * 128; t += 256) sW[t] = W[t];
  __syncthreads();
  int j = threadIdx.x & 127, half = threadIdx.x >> 7;
  float bj = b[j];
  for (int n = blockIdx.x * 2 + half; n < M; n += gridDim.x * 2){
    const float* xr = x + (size_t)n * K;
    float acc = bj;
    #pragma unroll
    for (int k = 0; k < K; k++) acc += xr[k] * sW[k * 128 + j];
    h[(size_t)n * H + j] = acc;
  }
}

// ---------- per-layer scalar edge coefficients ----------
__global__ void coeff_k(const float* __restrict__ gWe, const float* __restrict__ gae,
    const float* __restrict__ Wee, const float* __restrict__ bee, float* __restrict__ coeff)
{
  __shared__ float red[4];
  int t = threadIdx.x;  // 0..127
  for (int i = 0; i < NL; i++){
    const float* Wr = gWe + ((size_t)i * H + t) * H;
    const float* ga = gae + (size_t)i * H;
    float w = 0.f;
    for (int k = 0; k < H; k++) w += Wr[k] * ga[k];
    float pc = Wee[t] * w, pd = bee[t] * w;
    pc = wsum(pc); pd = wsum(pd);
    if ((t & 63) == 0){ red[(t >> 6) * 2 + 0] = pc; red[(t >> 6) * 2 + 1] = pd; }
    __syncthreads();
    if (t == 0){ coeff[i] = red[0] + red[2]; coeff[NL + i] = red[1] + red[3]; }
    __syncthreads();
  }
}

// ---------- LayerNorm -> bf16 xn (used once, after embed) ----------
__global__ __launch_bounds__(256) void ln_k(const float* __restrict__ hin,
    const float* __restrict__ g, const float* __restrict__ b,
    __hip_bfloat16* __restrict__ xn, int M)
{
  int lane = threadIdx.x & 63, wid = threadIdx.x >> 6;
  int n = blockIdx.x * 4 + wid;
  if (n >= M) return;
  const float* row = hin + (size_t)n * H;
  float x0 = row[lane], x1 = row[lane + 64];
  float mu = wsum(x0 + x1) * (1.f / H);
  float d0 = x0 - mu, d1 = x1 - mu;
  float var = wsum(d0 * d0 + d1 * d1) * (1.f / H);
  float rs = rsqrtf(var + 1e-5f);
  xn[(size_t)n * H + lane]      = __float2bfloat16(d0 * rs * g[lane]      + b[lane]);
  xn[(size_t)n * H + lane + 64] = __float2bfloat16(d1 * rs * g[lane + 64] + b[lane + 64]);
}

// ---------- dual dot products per node (wells only) ----------
__global__ __launch_bounds__(256) void dot2_k(const float* __restrict__ X,
    const float* __restrict__ va, float* __restrict__ oa, int M)
{
  int lane = threadIdx.x & 63, wid = threadIdx.x >> 6;
  int n = blockIdx.x * 4 + wid;
  if (n >= M) return;
  const float* row = X + (size_t)n * H;
  float a = wsum(row[lane] * va[lane] + row[lane + 64] * va[lane + 64]);
  if (lane == 0) oa[n] = a;
}

// ---------- MFMA GEMM + optional fused attention dots ----------
__global__ __launch_bounds__(512, 4) void gemm_mfma_k(
    const __hip_bfloat16* __restrict__ A, const __hip_bfloat16* __restrict__ WT,
    float* __restrict__ C, const float* __restrict__ va, const float* __restrict__ vb,
    float* __restrict__ oa, float* __restrict__ ob, int M)
{
  __shared__ __hip_bfloat16 sX[128 * 128];
  __shared__ __hip_bfloat16 sW[128 * 128];
  const int tid = threadIdx.x;
  const int lane = tid & 63, w = tid >> 6;
  const int n0 = blockIdx.x * 128;
  const int rw = w * 16;
  const int lr = lane & 15, lk = lane >> 4;

  for (int c = tid; c < 2048; c += 512){
    int r = c >> 4, s = c & 15;
    int row = n0 + r;
    uint4 v = make_uint4(0u, 0u, 0u, 0u);
    if (row < M) v = *(const uint4*)(A + (size_t)row * 128 + s * 8);
    *(uint4*)((char*)sX + r * 256 + ((s * 16) ^ ((r & 7) << 4))) = v;
  }
  for (int c = tid; c < 2048; c += 512){
    int r = c >> 4, s = c & 15;
    uint4 v = *(const uint4*)(WT + (size_t)r * 128 + s * 8);
    *(uint4*)((char*)sW + r * 256 + ((s * 16) ^ ((r & 7) << 4))) = v;
  }
  __syncthreads();

  f32x4 acc[8];
  #pragma unroll
  for (int i = 0; i < 8; i++) acc[i] = (f32x4){0.f, 0.f, 0.f, 0.f};
  #pragma unroll
  for (int ks = 0; ks < 4; ks++){
    int arow = rw + lr;
    int ak = ks * 32 + lk * 8;
    bf16x8 a = *(const bf16x8*)((const char*)sX + arow * 256 + ((ak * 2) ^ ((arow & 7) << 4)));
    #pragma unroll
    for (int nt = 0; nt < 8; nt++){
      int brow = nt * 16 + lr;
      bf16x8 b = *(const bf16x8*)((const char*)sW + brow * 256 + ((ak * 2) ^ ((brow & 7) << 4)));
      acc[nt] = MFMA16(a, b, acc[nt]);
    }
  }
  #pragma unroll
  for (int nt = 0; nt < 8; nt++){
    int col = nt * 16 + lr;
    #pragma unroll
    for (int r = 0; r < 4; r++){
      int row = n0 + rw + lk * 4 + r;
      if (row < M) C[(size_t)row * 128 + col] = acc[nt][r];
    }
  }
  if (va){
    float vac[8], vbc[8];
    #pragma unroll
    for (int nt = 0; nt < 8; nt++){
      vac[nt] = va[nt * 16 + lr];
      vbc[nt] = vb ? vb[nt * 16 + lr] : 0.f;
    }
    #pragma unroll
    for (int r = 0; r < 4; r++){
      float da = 0.f, db = 0.f;
      #pragma unroll
      for (int nt = 0; nt < 8; nt++){
        da += acc[nt][r] * vac[nt];
        db += acc[nt][r] * vbc[nt];
      }
      #pragma unroll
      for (int o = 1; o < 16; o <<= 1){
        da += __shfl_xor(da, o, 64);
        db += __shfl_xor(db, o, 64);
      }
      int row = n0 + rw + lk * 4 + r;
      if (lr == 0 && row < M){
        oa[row] = da;
        if (ob) ob[row] = db;
      }
    }
  }
}

// ---------- MFMA fused FFN: h += relu(xn@W1+b1)@W2 + b2, epilogue LN or bf16 ----------
__global__ __launch_bounds__(512, 4) void ffn_mfma_k(
    const __hip_bfloat16* __restrict__ xn, float* __restrict__ h,
    const __hip_bfloat16* __restrict__ W1T, const float* __restrict__ b1,
    const __hip_bfloat16* __restrict__ W2T, const float* __restrict__ b2,
    const float* __restrict__ lng, const float* __restrict__ lnb,
    __hip_bfloat16* __restrict__ xout, int mode, int M)   // mode 0: LN->xout, 1: bf16->xout
{
  __shared__ __hip_bfloat16 sX[128 * 128];
  __shared__ __hip_bfloat16 sW1[DC * 128];
  __shared__ __hip_bfloat16 sW2[128 * DC];
  __shared__ __hip_bfloat16 sT[128 * DC];
  const int tid = threadIdx.x;
  const int lane = tid & 63, w = tid >> 6;
  const int n0 = blockIdx.x * 128;
  const int rw = w * 16;
  const int lr = lane & 15, lk = lane >> 4;

  for (int c = tid; c < 2048; c += 512){
    int r = c >> 4, s = c & 15;
    int row = n0 + r;
    uint4 v = make_uint4(0u, 0u, 0u, 0u);
    if (row < M) v = *(const uint4*)(xn + (size_t)row * 128 + s * 8);
    *(uint4*)((char*)sX + r * 256 + ((s * 16) ^ ((r & 7) << 4))) = v;
  }

  f32x4 acc2[8];
  #pragma unroll
  for (int i = 0; i < 8; i++) acc2[i] = (f32x4){0.f, 0.f, 0.f, 0.f};

  for (int ch = 0; ch < DFF / DC; ch++){
    __syncthreads();
    for (int c = tid; c < 1024; c += 512){
      int r = c >> 4, s = c & 15;
      uint4 v = *(const uint4*)(W1T + (size_t)(ch * DC + r) * 128 + s * 8);
      *(uint4*)((char*)sW1 + r * 256 + ((s * 16) ^ ((r & 7) << 4))) = v;
    }
    for (int c = tid; c < 1024; c += 512){
      int r = c >> 3, s = c & 7;
      uint4 v = *(const uint4*)(W2T + (size_t)r * DFF + ch * DC + s * 8);
      *(uint4*)((char*)sW2 + r * 128 + ((s * 16) ^ ((r & 7) << 4))) = v;
    }
    __syncthreads();

    f32x4 acc1[4];
    #pragma unroll
    for (int i = 0; i < 4; i++) acc1[i] = (f32x4){0.f, 0.f, 0.f, 0.f};
    #pragma unroll
    for (int ks = 0; ks < 4; ks++){
      int arow = rw + lr;
      int ak = ks * 32 + lk * 8;
      bf16x8 a = *(const bf16x8*)((const char*)sX + arow * 256 + ((ak * 2) ^ ((arow & 7) << 4)));
      #pragma unroll
      for (int nt = 0; nt < 4; nt++){
        int brow = nt * 16 + lr;
        bf16x8 b = *(const bf16x8*)((const char*)sW1 + brow * 256 + ((ak * 2) ^ ((brow & 7) << 4)));
        acc1[nt] = MFMA16(a, b, acc1[nt]);
      }
    }
    #pragma unroll
    for (int nt = 0; nt < 4; nt++){
      int col = nt * 16 + lr;
      float bb = b1[ch * DC + col];
      #pragma unroll
      for (int r = 0; r < 4; r++){
        int row = rw + lk * 4 + r;
        float v = fmaxf(acc1[nt][r] + bb, 0.f);
        *(__hip_bfloat16*)((char*)sT + row * 128 + ((col * 2) ^ ((row & 7) << 4))) =
            __float2bfloat16(v);
      }
    }
    asm volatile("s_waitcnt lgkmcnt(0)" ::: "memory");

    #pragma unroll
    for (int ks = 0; ks < 2; ks++){
      int arow = rw + lr;
      int ak = ks * 32 + lk * 8;
      bf16x8 a = *(const bf16x8*)((const char*)sT + arow * 128 + ((ak * 2) ^ ((arow & 7) << 4)));
      #pragma unroll
      for (int nt = 0; nt < 8; nt++){
        int brow = nt * 16 + lr;
        bf16x8 b = *(const bf16x8*)((const char*)sW2 + brow * 128 + ((ak * 2) ^ ((brow & 7) << 4)));
        acc2[nt] = MFMA16(a, b, acc2[nt]);
      }
    }
  }

  // epilogue: h += acc2 + b2; then LN -> xout (mode 0) or bf16 -> xout (mode 1)
  float b2c[8];
  #pragma unroll
  for (int nt = 0; nt < 8; nt++) b2c[nt] = b2[nt * 16 + lr];

  #pragma unroll
  for (int r = 0; r < 4; r++){
    int row = n0 + rw + lk * 4 + r;
    bool ok = row < M;
    float val[8]; float sum = 0.f;
    #pragma unroll
    for (int nt = 0; nt < 8; nt++){
      int col = nt * 16 + lr;
      float hv = ok ? h[(size_t)row * 128 + col] : 0.f;
      val[nt] = hv + acc2[nt][r] + b2c[nt];
      sum += val[nt];
    }
    if (mode == 0){
      #pragma unroll
      for (int o = 1; o < 16; o <<= 1) sum += __shfl_xor(sum, o, 64);
      float mu = sum * (1.f / 128.f);
      float vs = 0.f;
      #pragma unroll
      for (int nt = 0; nt < 8; nt++){ float d = val[nt] - mu; vs += d * d; }
      #pragma unroll
      for (int o = 1; o < 16; o <<= 1) vs += __shfl_xor(vs, o, 64);
      float rs = rsqrtf(vs * (1.f / 128.f) + 1e-5f);
      #pragma unroll
      for (int nt = 0; nt < 8; nt++){
        int col = nt * 16 + lr;
        if (ok){
          h[(size_t)row * 128 + col] = val[nt];
          xout[(size_t)row * 128 + col] =
              __float2bfloat16((val[nt] - mu) * rs * lng[col] + lnb[col]);
        }
      }
    } else {
      #pragma unroll
      for (int nt = 0; nt < 8; nt++){
        int col = nt * 16 + lr;
        if (ok){
          h[(size_t)row * 128 + col] = val[nt];
          xout[(size_t)row * 128 + col] = __float2bfloat16(val[nt]);
        }
      }
    }
  }
}

// ---------- fp32 GEMM (tiny well matmul) ----------
__global__ __launch_bounds__(256) void gemm128_k(const float* __restrict__ A,
    const float* __restrict__ Bm, float* __restrict__ C, int M)
{
  __shared__ float sB[32 * 128];
  __shared__ float sA[64 * 33];
  const int tid = threadIdx.x;
  const int n0 = blockIdx.x * 64;
  const int j4 = (tid & 31) * 4;
  const int rB = (tid >> 5) * 8;
  float acc[8][4];
  #pragma unroll
  for (int r = 0; r < 8; r++){ acc[r][0]=acc[r][1]=acc[r][2]=acc[r][3]=0.f; }
  for (int kc = 0; kc < 128; kc += 32){
    for (int t = tid; t < 4096; t += 256){
      int kk = t >> 7, j = t & 127;
      sB[kk * 128 + j] = Bm[(size_t)(kc + kk) * H + j];
    }
    for (int t = tid; t < 2048; t += 256){
      int n = t >> 5, kk = t & 31; int row = n0 + n;
      sA[n * 33 + kk] = (row < M) ? A[(size_t)row * H + kc + kk] : 0.f;
    }
    __syncthreads();
    #pragma unroll 8
    for (int kk = 0; kk < 32; kk++){
      float4 bv = *(const float4*)&sB[kk * 128 + j4];
      #pragma unroll
      for (int r = 0; r < 8; r++){
        float av = sA[(rB + r) * 33 + kk];
        acc[r][0] += av * bv.x; acc[r][1] += av * bv.y;
        acc[r][2] += av * bv.z; acc[r][3] += av * bv.w;
      }
    }
    __syncthreads();
  }
  #pragma unroll
  for (int r = 0; r < 8; r++){
    int row = n0 + rB + r;
    if (row < M){
      float4 o; o.x = acc[r][0]; o.y = acc[r][1]; o.z = acc[r][2]; o.w = acc[r][3];
      *(float4*)&C[(size_t)row * H + j4] = o;
    }
  }
}

// ---------- CSR build ----------
__global__ void count_k(const int* __restrict__ dst, int* __restrict__ cnt, int NE){
  int e = blockIdx.x * 256 + threadIdx.x;
  if (e < NE) atomicAdd(&cnt[dst[e]], 1);
}
__global__ void scan1_k(const int* __restrict__ in, int* __restrict__ out,
                        int* __restrict__ bsum, int N){
  __shared__ int sd[256];
  int tid = threadIdx.x;
  int base = blockIdx.x * 1024 + tid * 4;
  int v0 = (base + 0 < N) ? in[base + 0] : 0;
  int v1 = (base + 1 < N) ? in[base + 1] : 0;
  int v2 = (base + 2 < N) ? in[base + 2] : 0;
  int v3 = (base + 3 < N) ? in[base + 3] : 0;
  sd[tid] = v0 + v1 + v2 + v3;
  __syncthreads();
  for (int off = 1; off < 256; off <<= 1){
    int t = (tid >= off) ? sd[tid - off] : 0;
    __syncthreads();
    sd[tid] += t;
    __syncthreads();
  }
  int run = (tid > 0) ? sd[tid - 1] : 0;
  run += v0; if (base + 0 < N) out[base + 0] = run;
  run += v1; if (base + 1 < N) out[base + 1] = run;
  run += v2; if (base + 2 < N) out[base + 2] = run;
  run += v3; if (base + 3 < N) out[base + 3] = run;
  if (tid == 255) bsum[blockIdx.x] = sd[255];
}
__global__ void scan2_k(int* __restrict__ bs, int NB){
  __shared__ int sd[256];
  int tid = threadIdx.x;
  int base = tid * 4;
  int v0 = (base + 0 < NB) ? bs[base + 0] : 0;
  int v1 = (base + 1 < NB) ? bs[base + 1] : 0;
  int v2 = (base + 2 < NB) ? bs[base + 2] : 0;
  int v3 = (base + 3 < NB) ? bs[base + 3] : 0;
  sd[tid] = v0 + v1 + v2 + v3;
  __syncthreads();
  for (int off = 1; off < 256; off <<= 1){
    int t = (tid >= off) ? sd[tid - off] : 0;
    __syncthreads();
    sd[tid] += t;
    __syncthreads();
  }
  int run = (tid > 0) ? sd[tid - 1] : 0;
  run += v0; if (base + 0 < NB) bs[base + 0] = run;
  run += v1; if (base + 1 < NB) bs[base + 1] = run;
  run += v2; if (base + 2 < NB) bs[base + 2] = run;
  run += v3; if (base + 3 < NB) bs[base + 3] = run;
}
__global__ void scan3_k(int* __restrict__ out, const int* __restrict__ bsum, int N){
  int b = blockIdx.x;
  if (b == 0) return;
  int add = bsum[b - 1];
  int i = b * 1024 + threadIdx.x * 4;
  #pragma unroll
  for (int j = 0; j < 4; j++) if (i + j < N) out[i + j] += add;
}
__global__ void initfill_k(const int* __restrict__ incl, int* __restrict__ fill, int N){
  int i = blockIdx.x * 256 + threadIdx.x;
  if (i < N) fill[i] = (i == 0) ? 0 : incl[i - 1];
}
__global__ void fill_k(const int* __restrict__ dst, int* __restrict__ fill,
                       int* __restrict__ csr, int NE){
  int e = blockIdx.x * 256 + threadIdx.x;
  if (e < NE){
    int p = atomicAdd(&fill[dst[e]], 1);
    csr[p] = e;
  }
}

// ---------- fused GAT gather: online softmax + message + residual + LN ----------
__global__ __launch_bounds__(256) void gat_k(
    const int* __restrict__ incl, const int* __restrict__ csr,
    const int* __restrict__ src, const float* __restrict__ attr,
    const float* __restrict__ coeff, int ci,
    const float* __restrict__ as_, const float* __restrict__ ad_,
    const float* __restrict__ X, float* __restrict__ hout,
    const float* __restrict__ gb, const float* __restrict__ g,
    const float* __restrict__ b, __hip_bfloat16* __restrict__ xn,
    int M, int residual)
{
  int lane = threadIdx.x & 63, wid = threadIdx.x >> 6;
  int n = blockIdx.x * 4 + wid;
  if (n >= M) return;
  int beg = (n == 0) ? 0 : incl[n - 1];
  int end = incl[n];
  float c0 = 0.f, c1 = 0.f;
  if (attr){ c0 = coeff[ci]; c1 = coeff[NL + ci]; }
  float adn = ad_[n];
  float m = -1e30f, s = 0.f, acc0 = 0.f, acc1 = 0.f;
  for (int base = beg; base < end; base += 64){
    int idx = base + lane;
    bool valid = idx < end;
    int e = valid ? csr[idx] : 0;
    int sv = valid ? src[e] : 0;
    float a = -1e30f;
    if (valid){
      a = as_[sv] + adn;
      if (attr) a += attr[e] * c0 + c1;
      a = (a > 0.f) ? a : 0.2f * a;
    }
    float cm = wmax(a);
    float nm = fmaxf(m, cm);
    float sc = expf(m - nm);     // first chunk: exp(-1e30-x) -> 0
    acc0 *= sc; acc1 *= sc; s *= sc;
    float p = valid ? expf(a - nm) : 0.f;
    s += wsum(p);
    m = nm;
    int cnt = min(64, end - base);
    for (int t = 0; t < cnt; t++){
      float pt = __shfl(p, t, 64);
      int st = __shfl(sv, t, 64);
      const float* xr = X + (size_t)st * H;
      acc0 += pt * xr[lane];
      acc1 += pt * xr[lane + 64];
    }
  }
  float inv = (s == 0.f) ? 0.f : 1.f / s;
  acc0 *= inv; acc1 *= inv;
  if (residual){
    float hv0 = hout[(size_t)n * H + lane]      + acc0 + gb[lane];
    float hv1 = hout[(size_t)n * H + lane + 64] + acc1 + gb[lane + 64];
    hout[(size_t)n * H + lane]      = hv0;
    hout[(size_t)n * H + lane + 64] = hv1;
    float mu = wsum(hv0 + hv1) * (1.f / H);
    float d0 = hv0 - mu, d1 = hv1 - mu;
    float var = wsum(d0 * d0 + d1 * d1) * (1.f / H);
    float rs = rsqrtf(var + 1e-5f);
    xn[(size_t)n * H + lane]      = __float2bfloat16(d0 * rs * g[lane]      + b[lane]);
    xn[(size_t)n * H + lane + 64] = __float2bfloat16(d1 * rs * g[lane + 64] + b[lane + 64]);
  } else {
    hout[(size_t)n * H + lane]      = acc0;
    hout[(size_t)n * H + lane + 64] = acc1;
  }
}

// ---------- final well MLP ----------
__global__ __launch_bounds__(128) void mlp_k(const float* __restrict__ hwell,
    const float* __restrict__ wb, const float* __restrict__ mW1,
    const float* __restrict__ mb1, const float* __restrict__ mW2,
    const float* __restrict__ mb2, float* __restrict__ out)
{
  __shared__ float sH[128], sT[128];
  int n = blockIdx.x, j = threadIdx.x;
  sH[j] = hwell[(size_t)n * H + j] + wb[j];
  __syncthreads();
  float a = mb1[j];
  for (int k = 0; k < 128; k++) a += sH[k] * mW1[k * 128 + j];
  sT[j] = fmaxf(a, 0.f);
  __syncthreads();
  if (j < 75){
    float o = mb2[j];
    for (int k = 0; k < 128; k++) o += sT[k] * mW2[k * 75 + j];
    out[(size_t)n * 75 + j] = o;
  }
}

extern "C" void kernel_launch(void* const* d_in, const int* in_sizes, int n_in,
                              void* d_out, int out_size, void* d_ws, size_t ws_size,
                              hipStream_t stream)
{
  (void)in_sizes; (void)n_in; (void)out_size; (void)ws_size;
  const float* cell_x = (const float*)d_in[0];
  const float* well_x = (const float*)d_in[1];
  const int*   eidx   = (const int*)d_in[2];
  const float* eattr  = (const float*)d_in[3];
  const int*   wsrc   = (const int*)d_in[4];
  const int*   wdst   = (const int*)d_in[5];
  const float* W_cell = (const float*)d_in[6];
  const float* b_cell = (const float*)d_in[7];
  const float* W_well = (const float*)d_in[8];
  const float* b_well = (const float*)d_in[9];
  const float* W_ee   = (const float*)d_in[10];
  const float* b_ee   = (const float*)d_in[11];
  const float* gW     = (const float*)d_in[12];
  const float* gas    = (const float*)d_in[13];
  const float* gad    = (const float*)d_in[14];
  const float* gae    = (const float*)d_in[15];
  const float* gWe    = (const float*)d_in[16];
  const float* gb     = (const float*)d_in[17];
  const float* n1g    = (const float*)d_in[18];
  const float* n1b    = (const float*)d_in[19];
  const float* fW1    = (const float*)d_in[20];
  const float* fb1    = (const float*)d_in[21];
  const float* fW2    = (const float*)d_in[22];
  const float* fb2    = (const float*)d_in[23];
  const float* n2g    = (const float*)d_in[24];
  const float* n2b    = (const float*)d_in[25];
  const float* wW     = (const float*)d_in[26];
  const float* was    = (const float*)d_in[27];
  const float* wad    = (const float*)d_in[28];
  const float* wb     = (const float*)d_in[29];
  const float* mW1    = (const float*)d_in[30];
  const float* mb1    = (const float*)d_in[31];
  const float* mW2    = (const float*)d_in[32];
  const float* mb2    = (const float*)d_in[33];

  const int* src = eidx;
  const int* dst = eidx + NE_CC;

  char* wsb = (char*)d_ws;
  size_t off = 0;
  auto alloc = [&](size_t bytes) -> void* {
    void* p = wsb + off; off += (bytes + 255) & ~(size_t)255; return p;
  };
  float* h      = (float*)alloc((size_t)NC * H * 4);
  float* hs     = (float*)alloc((size_t)NC * H * 4);
  __hip_bfloat16* xnbf = (__hip_bfloat16*)alloc((size_t)NC * H * 2);
  float* as_    = (float*)alloc((size_t)NC * 4);
  float* ad_    = (float*)alloc((size_t)NC * 4);
  float* hw     = (float*)alloc((size_t)NW * H * 4);
  float* hwp    = (float*)alloc((size_t)NW * H * 4);
  float* hwell  = (float*)alloc((size_t)NW * H * 4);
  float* coeff  = (float*)alloc(64);
  __hip_bfloat16* gWT = (__hip_bfloat16*)alloc((size_t)NL * H * H * 2);
  __hip_bfloat16* W1T = (__hip_bfloat16*)alloc((size_t)NL * DFF * H * 2);
  __hip_bfloat16* W2T = (__hip_bfloat16*)alloc((size_t)NL * H * DFF * 2);
  __hip_bfloat16* wWT = (__hip_bfloat16*)alloc((size_t)H * H * 2);
  int* cntC  = (int*)alloc((size_t)NC * 4);
  int* inclC = (int*)alloc((size_t)NC * 4);
  int* fillC = (int*)alloc((size_t)NC * 4);
  int* csrC  = (int*)alloc((size_t)NE_CC * 4);
  int* inclW = (int*)alloc((size_t)NW * 4);
  int* fillW = (int*)alloc((size_t)NW * 4);
  int* csrW  = (int*)alloc((size_t)NE_CW * 4);
  int* bsum  = (int*)alloc(1024 * 4);

  const int eBlocks  = (NE_CC + 255) / 256;
  const int ewBlocks = (NE_CW + 255) / 256;
  const int NBC = (NC + 1023) / 1024;
  const int NBW = (NW + 1023) / 1024;

  // ---- CSR build (c2c) ----
  hipMemsetAsync(cntC, 0, (size_t)NC * 4, stream);
  count_k<<<eBlocks, 256, 0, stream>>>(dst, cntC, NE_CC);
  scan1_k<<<NBC, 256, 0, stream>>>(cntC, inclC, bsum, NC);
  scan2_k<<<1, 256, 0, stream>>>(bsum, NBC);
  scan3_k<<<NBC, 256, 0, stream>>>(inclC, bsum, NC);
  initfill_k<<<(NC + 255) / 256, 256, 0, stream>>>(inclC, fillC, NC);
  fill_k<<<eBlocks, 256, 0, stream>>>(dst, fillC, csrC, NE_CC);
  // ---- CSR build (c2w) ----
  hipMemsetAsync(fillW, 0, (size_t)NW * 4, stream);   // use fillW as cnt first
  count_k<<<ewBlocks, 256, 0, stream>>>(wdst, fillW, NE_CW);
  scan1_k<<<NBW, 256, 0, stream>>>(fillW, inclW, bsum, NW);
  scan2_k<<<1, 256, 0, stream>>>(bsum, NBW);
  scan3_k<<<NBW, 256, 0, stream>>>(inclW, bsum, NW);
  initfill_k<<<(NW + 255) / 256, 256, 0, stream>>>(inclW, fillW, NW);
  fill_k<<<ewBlocks, 256, 0, stream>>>(wdst, fillW, csrW, NE_CW);

  // ---- weight prep ----
  prep_T_k<<<192, 256, 0, stream>>>(gW, gWT, 128, 128, NL);
  prep_T_k<<<768, 256, 0, stream>>>(fW1, W1T, 128, 512, NL);
  prep_T_k<<<768, 256, 0, stream>>>(fW2, W2T, 512, 128, NL);
  prep_T_k<<<64, 256, 0, stream>>>(wW, wWT, 128, 128, 1);

  embed_k<32><<<2048, 256, 0, stream>>>(cell_x, W_cell, b_cell, h, NC);
  embed_k<16><<<250, 256, 0, stream>>>(well_x, W_well, b_well, hw, NW);
  coeff_k<<<1, 128, 0, stream>>>(gWe, gae, W_ee, b_ee, coeff);

  const int lnBlocks = (NC + 3) / 4;
  const int mfmaBlocks = (NC + 127) / 128;

  ln_k<<<lnBlocks, 256, 0, stream>>>(h, n1g, n1b, xnbf, NC);  // layer-0 LN1

  for (int i = 0; i < NL; i++){
    gemm_mfma_k<<<mfmaBlocks, 512, 0, stream>>>(xnbf, gWT + (size_t)i * H * H, hs,
        gas + i * H, gad + i * H, as_, ad_, NC);
    gat_k<<<lnBlocks, 256, 0, stream>>>(inclC, csrC, src, eattr, coeff, i,
        as_, ad_, hs, h, gb + i * H, n2g + i * H, n2b + i * H, xnbf, NC, 1);
    int last = (i == NL - 1);
    ffn_mfma_k<<<mfmaBlocks, 512, 0, stream>>>(xnbf, h,
        W1T + (size_t)i * DFF * H, fb1 + (size_t)i * DFF,
        W2T + (size_t)i * H * DFF, fb2 + (size_t)i * H,
        n1g + ((i + 1) % NL) * H, n1b + ((i + 1) % NL) * H,
        xnbf, last ? 1 : 0, NC);
  }

  // cell -> well bipartite GAT (xnbf now holds bf16(h))
  gemm_mfma_k<<<mfmaBlocks, 512, 0, stream>>>(xnbf, wWT, hs,
      was, nullptr, as_, nullptr, NC);                          // hc + as_
  gemm128_k<<<(NW + 63) / 64, 256, 0, stream>>>(hw, wW, hwp, NW);
  dot2_k<<<(NW + 3) / 4, 256, 0, stream>>>(hwp, wad, ad_, NW);
  gat_k<<<(NW + 3) / 4, 256, 0, stream>>>(inclW, csrW, wsrc, nullptr, coeff, 0,
      as_, ad_, hs, hwell, nullptr, nullptr, nullptr, nullptr, NW, 0);
  mlp_k<<<NW, 128, 0, stream>>>(hwell, wb, mW1, mb1, mW2, mb2, (float*)d_out);
}

// Round 4
// 803.961 us; speedup vs baseline: 4.2602x; 1.0170x over previous
//
#include <hip/hip_runtime.h>
#include <hip/hip_bf16.h>

#define NC 100000
#define NW 500
#define NE_CC 600000
#define NE_CW 25000
#define H 128
#define NL 3
#define DFF 512
#define DC 64

typedef __bf16 bf16x8 __attribute__((ext_vector_type(8)));
typedef float f32x4 __attribute__((ext_vector_type(4)));
#define MFMA16(a,b,c) __builtin_amdgcn_mfma_f32_16x16x32_bf16(a,b,c,0,0,0)

__device__ __forceinline__ float wsum(float v){
  #pragma unroll
  for (int o = 32; o; o >>= 1) v += __shfl_xor(v, o, 64);
  return v;
}
__device__ __forceinline__ float wmax(float v){
  #pragma unroll
  for (int o = 32; o; o >>= 1) v = fmaxf(v, __shfl_xor(v, o, 64));
  return v;
}

// ---------- weight prep: out[l][n][k] = bf16(in[l][k][n]) ----------
__global__ void prep_T_k(const float* __restrict__ in, __hip_bfloat16* __restrict__ out,
                         int K, int N, int nmat)
{
  size_t tot = (size_t)nmat * K * N;
  for (size_t i = blockIdx.x * 256 + threadIdx.x; i < tot; i += (size_t)gridDim.x * 256){
    size_t l = i / ((size_t)K * N);
    size_t rem = i - l * (size_t)K * N;
    int n = (int)(rem / K), k = (int)(rem % K);
    out[i] = __float2bfloat16(in[l * (size_t)K * N + (size_t)k * N + n]);
  }
}

// ---------- embeddings ----------
template<int K>
__global__ __launch_bounds__(256) void embed_k(const float* __restrict__ x,
    const float* __restrict__ W, const float* __restrict__ b,
    float* __restrict__ h, int M)
{
  __shared__ float sW[K * 128];
  for (int t = threadIdx.x; t < K * 128; t += 256) sW[t] = W[t];
  __syncthreads();
  int j = threadIdx.x & 127, half = threadIdx.x >> 7;
  float bj = b[j];
  for (int n = blockIdx.x * 2 + half; n < M; n += gridDim.x * 2){
    const float* xr = x + (size_t)n * K;
    float acc = bj;
    #pragma unroll
    for (int k = 0; k < K; k++) acc += xr[k] * sW[k * 128 + j];
    h[(size_t)n * H + j] = acc;
  }
}

// ---------- per-layer scalar edge coefficients ----------
__global__ void coeff_k(const float* __restrict__ gWe, const float* __restrict__ gae,
    const float* __restrict__ Wee, const float* __restrict__ bee, float* __restrict__ coeff)
{
  __shared__ float red[4];
  int t = threadIdx.x;  // 0..127
  for (int i = 0; i < NL; i++){
    const float* Wr = gWe + ((size_t)i * H + t) * H;
    const float* ga = gae + (size_t)i * H;
    float w = 0.f;
    for (int k = 0; k < H; k++) w += Wr[k] * ga[k];
    float pc = Wee[t] * w, pd = bee[t] * w;
    pc = wsum(pc); pd = wsum(pd);
    if ((t & 63) == 0){ red[(t >> 6) * 2 + 0] = pc; red[(t >> 6) * 2 + 1] = pd; }
    __syncthreads();
    if (t == 0){ coeff[i] = red[0] + red[2]; coeff[NL + i] = red[1] + red[3]; }
    __syncthreads();
  }
}

// ---------- LayerNorm -> bf16 xn (used once, after embed) ----------
__global__ __launch_bounds__(256) void ln_k(const float* __restrict__ hin,
    const float* __restrict__ g, const float* __restrict__ b,
    __hip_bfloat16* __restrict__ xn, int M)
{
  int lane = threadIdx.x & 63, wid = threadIdx.x >> 6;
  int n = blockIdx.x * 4 + wid;
  if (n >= M) return;
  const float* row = hin + (size_t)n * H;
  float x0 = row[lane], x1 = row[lane + 64];
  float mu = wsum(x0 + x1) * (1.f / H);
  float d0 = x0 - mu, d1 = x1 - mu;
  float var = wsum(d0 * d0 + d1 * d1) * (1.f / H);
  float rs = rsqrtf(var + 1e-5f);
  xn[(size_t)n * H + lane]      = __float2bfloat16(d0 * rs * g[lane]      + b[lane]);
  xn[(size_t)n * H + lane + 64] = __float2bfloat16(d1 * rs * g[lane + 64] + b[lane + 64]);
}

// ---------- dot product per node (wells only) ----------
__global__ __launch_bounds__(256) void dot2_k(const float* __restrict__ X,
    const float* __restrict__ va, float* __restrict__ oa, int M)
{
  int lane = threadIdx.x & 63, wid = threadIdx.x >> 6;
  int n = blockIdx.x * 4 + wid;
  if (n >= M) return;
  const float* row = X + (size_t)n * H;
  float a = wsum(row[lane] * va[lane] + row[lane + 64] * va[lane + 64]);
  if (lane == 0) oa[n] = a;
}

// ---------- MFMA GEMM (+fused attention dots, optional fp32/bf16 C) ----------
__global__ __launch_bounds__(512, 4) void gemm_mfma_k(
    const __hip_bfloat16* __restrict__ A, const __hip_bfloat16* __restrict__ WT,
    float* __restrict__ C, __hip_bfloat16* __restrict__ Cbf,
    const float* __restrict__ va, const float* __restrict__ vb,
    float* __restrict__ oa, float* __restrict__ ob, int M)
{
  __shared__ __hip_bfloat16 sX[128 * 128];
  __shared__ __hip_bfloat16 sW[128 * 128];
  const int tid = threadIdx.x;
  const int lane = tid & 63, w = tid >> 6;
  const int n0 = blockIdx.x * 128;
  const int rw = w * 16;
  const int lr = lane & 15, lk = lane >> 4;

  for (int c = tid; c < 2048; c += 512){
    int r = c >> 4, s = c & 15;
    int row = n0 + r;
    uint4 v = make_uint4(0u, 0u, 0u, 0u);
    if (row < M) v = *(const uint4*)(A + (size_t)row * 128 + s * 8);
    *(uint4*)((char*)sX + r * 256 + ((s * 16) ^ ((r & 7) << 4))) = v;
  }
  for (int c = tid; c < 2048; c += 512){
    int r = c >> 4, s = c & 15;
    uint4 v = *(const uint4*)(WT + (size_t)r * 128 + s * 8);
    *(uint4*)((char*)sW + r * 256 + ((s * 16) ^ ((r & 7) << 4))) = v;
  }
  __syncthreads();

  f32x4 acc[8];
  #pragma unroll
  for (int i = 0; i < 8; i++) acc[i] = (f32x4){0.f, 0.f, 0.f, 0.f};
  #pragma unroll
  for (int ks = 0; ks < 4; ks++){
    int arow = rw + lr;
    int ak = ks * 32 + lk * 8;
    bf16x8 a = *(const bf16x8*)((const char*)sX + arow * 256 + ((ak * 2) ^ ((arow & 7) << 4)));
    #pragma unroll
    for (int nt = 0; nt < 8; nt++){
      int brow = nt * 16 + lr;
      bf16x8 b = *(const bf16x8*)((const char*)sW + brow * 256 + ((ak * 2) ^ ((brow & 7) << 4)));
      acc[nt] = MFMA16(a, b, acc[nt]);
    }
  }
  #pragma unroll
  for (int nt = 0; nt < 8; nt++){
    int col = nt * 16 + lr;
    #pragma unroll
    for (int r = 0; r < 4; r++){
      int row = n0 + rw + lk * 4 + r;
      if (row < M){
        if (C)   C[(size_t)row * 128 + col] = acc[nt][r];
        if (Cbf) Cbf[(size_t)row * 128 + col] = __float2bfloat16(acc[nt][r]);
      }
    }
  }
  if (va){
    float vac[8], vbc[8];
    #pragma unroll
    for (int nt = 0; nt < 8; nt++){
      vac[nt] = va[nt * 16 + lr];
      vbc[nt] = vb ? vb[nt * 16 + lr] : 0.f;
    }
    #pragma unroll
    for (int r = 0; r < 4; r++){
      float da = 0.f, db = 0.f;
      #pragma unroll
      for (int nt = 0; nt < 8; nt++){
        da += acc[nt][r] * vac[nt];
        db += acc[nt][r] * vbc[nt];
      }
      #pragma unroll
      for (int o = 1; o < 16; o <<= 1){
        da += __shfl_xor(da, o, 64);
        db += __shfl_xor(db, o, 64);
      }
      int row = n0 + rw + lk * 4 + r;
      if (lr == 0 && row < M){
        oa[row] = da;
        if (ob) ob[row] = db;
      }
    }
  }
}

// ---------- MFMA fused FFN: h += relu(xn@W1+b1)@W2 + b2, epilogue LN or bf16 ----------
__global__ __launch_bounds__(512, 4) void ffn_mfma_k(
    const __hip_bfloat16* __restrict__ xn, float* __restrict__ h,
    const __hip_bfloat16* __restrict__ W1T, const float* __restrict__ b1,
    const __hip_bfloat16* __restrict__ W2T, const float* __restrict__ b2,
    const float* __restrict__ lng, const float* __restrict__ lnb,
    __hip_bfloat16* __restrict__ xout, int mode, int M)   // mode 0: LN->xout, 1: bf16->xout
{
  __shared__ __hip_bfloat16 sX[128 * 128];
  __shared__ __hip_bfloat16 sW1[DC * 128];
  __shared__ __hip_bfloat16 sW2[128 * DC];
  __shared__ __hip_bfloat16 sT[128 * DC];
  const int tid = threadIdx.x;
  const int lane = tid & 63, w = tid >> 6;
  const int n0 = blockIdx.x * 128;
  const int rw = w * 16;
  const int lr = lane & 15, lk = lane >> 4;

  for (int c = tid; c < 2048; c += 512){
    int r = c >> 4, s = c & 15;
    int row = n0 + r;
    uint4 v = make_uint4(0u, 0u, 0u, 0u);
    if (row < M) v = *(const uint4*)(xn + (size_t)row * 128 + s * 8);
    *(uint4*)((char*)sX + r * 256 + ((s * 16) ^ ((r & 7) << 4))) = v;
  }

  f32x4 acc2[8];
  #pragma unroll
  for (int i = 0; i < 8; i++) acc2[i] = (f32x4){0.f, 0.f, 0.f, 0.f};

  for (int ch = 0; ch < DFF / DC; ch++){
    __syncthreads();
    for (int c = tid; c < 1024; c += 512){
      int r = c >> 4, s = c & 15;
      uint4 v = *(const uint4*)(W1T + (size_t)(ch * DC + r) * 128 + s * 8);
      *(uint4*)((char*)sW1 + r * 256 + ((s * 16) ^ ((r & 7) << 4))) = v;
    }
    for (int c = tid; c < 1024; c += 512){
      int r = c >> 3, s = c & 7;
      uint4 v = *(const uint4*)(W2T + (size_t)r * DFF + ch * DC + s * 8);
      *(uint4*)((char*)sW2 + r * 128 + ((s * 16) ^ ((r & 7) << 4))) = v;
    }
    __syncthreads();

    f32x4 acc1[4];
    #pragma unroll
    for (int i = 0; i < 4; i++) acc1[i] = (f32x4){0.f, 0.f, 0.f, 0.f};
    #pragma unroll
    for (int ks = 0; ks < 4; ks++){
      int arow = rw + lr;
      int ak = ks * 32 + lk * 8;
      bf16x8 a = *(const bf16x8*)((const char*)sX + arow * 256 + ((ak * 2) ^ ((arow & 7) << 4)));
      #pragma unroll
      for (int nt = 0; nt < 4; nt++){
        int brow = nt * 16 + lr;
        bf16x8 b = *(const bf16x8*)((const char*)sW1 + brow * 256 + ((ak * 2) ^ ((brow & 7) << 4)));
        acc1[nt] = MFMA16(a, b, acc1[nt]);
      }
    }
    #pragma unroll
    for (int nt = 0; nt < 4; nt++){
      int col = nt * 16 + lr;
      float bb = b1[ch * DC + col];
      #pragma unroll
      for (int r = 0; r < 4; r++){
        int row = rw + lk * 4 + r;
        float v = fmaxf(acc1[nt][r] + bb, 0.f);
        *(__hip_bfloat16*)((char*)sT + row * 128 + ((col * 2) ^ ((row & 7) << 4))) =
            __float2bfloat16(v);
      }
    }
    asm volatile("s_waitcnt lgkmcnt(0)" ::: "memory");

    #pragma unroll
    for (int ks = 0; ks < 2; ks++){
      int arow = rw + lr;
      int ak = ks * 32 + lk * 8;
      bf16x8 a = *(const bf16x8*)((const char*)sT + arow * 128 + ((ak * 2) ^ ((arow & 7) << 4)));
      #pragma unroll
      for (int nt = 0; nt < 8; nt++){
        int brow = nt * 16 + lr;
        bf16x8 b = *(const bf16x8*)((const char*)sW2 + brow * 128 + ((ak * 2) ^ ((brow & 7) << 4)));
        acc2[nt] = MFMA16(a, b, acc2[nt]);
      }
    }
  }

  float b2c[8];
  #pragma unroll
  for (int nt = 0; nt < 8; nt++) b2c[nt] = b2[nt * 16 + lr];

  #pragma unroll
  for (int r = 0; r < 4; r++){
    int row = n0 + rw + lk * 4 + r;
    bool ok = row < M;
    float val[8]; float sum = 0.f;
    #pragma unroll
    for (int nt = 0; nt < 8; nt++){
      int col = nt * 16 + lr;
      float hv = ok ? h[(size_t)row * 128 + col] : 0.f;
      val[nt] = hv + acc2[nt][r] + b2c[nt];
      sum += val[nt];
    }
    if (mode == 0){
      #pragma unroll
      for (int o = 1; o < 16; o <<= 1) sum += __shfl_xor(sum, o, 64);
      float mu = sum * (1.f / 128.f);
      float vs = 0.f;
      #pragma unroll
      for (int nt = 0; nt < 8; nt++){ float d = val[nt] - mu; vs += d * d; }
      #pragma unroll
      for (int o = 1; o < 16; o <<= 1) vs += __shfl_xor(vs, o, 64);
      float rs = rsqrtf(vs * (1.f / 128.f) + 1e-5f);
      #pragma unroll
      for (int nt = 0; nt < 8; nt++){
        int col = nt * 16 + lr;
        if (ok){
          h[(size_t)row * 128 + col] = val[nt];
          xout[(size_t)row * 128 + col] =
              __float2bfloat16((val[nt] - mu) * rs * lng[col] + lnb[col]);
        }
      }
    } else {
      #pragma unroll
      for (int nt = 0; nt < 8; nt++){
        int col = nt * 16 + lr;
        if (ok){
          h[(size_t)row * 128 + col] = val[nt];
          xout[(size_t)row * 128 + col] = __float2bfloat16(val[nt]);
        }
      }
    }
  }
}

// ---------- fp32 GEMM (tiny well matmul) ----------
__global__ __launch_bounds__(256) void gemm128_k(const float* __restrict__ A,
    const float* __restrict__ Bm, float* __restrict__ C, int M)
{
  __shared__ float sB[32 * 128];
  __shared__ float sA[64 * 33];
  const int tid = threadIdx.x;
  const int n0 = blockIdx.x * 64;
  const int j4 = (tid & 31) * 4;
  const int rB = (tid >> 5) * 8;
  float acc[8][4];
  #pragma unroll
  for (int r = 0; r < 8; r++){ acc[r][0]=acc[r][1]=acc[r][2]=acc[r][3]=0.f; }
  for (int kc = 0; kc < 128; kc += 32){
    for (int t = tid; t < 4096; t += 256){
      int kk = t >> 7, j = t & 127;
      sB[kk * 128 + j] = Bm[(size_t)(kc + kk) * H + j];
    }
    for (int t = tid; t < 2048; t += 256){
      int n = t >> 5, kk = t & 31; int row = n0 + n;
      sA[n * 33 + kk] = (row < M) ? A[(size_t)row * H + kc + kk] : 0.f;
    }
    __syncthreads();
    #pragma unroll 8
    for (int kk = 0; kk < 32; kk++){
      float4 bv = *(const float4*)&sB[kk * 128 + j4];
      #pragma unroll
      for (int r = 0; r < 8; r++){
        float av = sA[(rB + r) * 33 + kk];
        acc[r][0] += av * bv.x; acc[r][1] += av * bv.y;
        acc[r][2] += av * bv.z; acc[r][3] += av * bv.w;
      }
    }
    __syncthreads();
  }
  #pragma unroll
  for (int r = 0; r < 8; r++){
    int row = n0 + rB + r;
    if (row < M){
      float4 o; o.x = acc[r][0]; o.y = acc[r][1]; o.z = acc[r][2]; o.w = acc[r][3];
      *(float4*)&C[(size_t)row * H + j4] = o;
    }
  }
}

// ---------- CSR build ----------
__global__ void count_k(const int* __restrict__ dst, int* __restrict__ cnt, int NE){
  int e = blockIdx.x * 256 + threadIdx.x;
  if (e < NE) atomicAdd(&cnt[dst[e]], 1);
}
__global__ void scan1_k(const int* __restrict__ in, int* __restrict__ out,
                        int* __restrict__ bsum, int N){
  __shared__ int sd[256];
  int tid = threadIdx.x;
  int base = blockIdx.x * 1024 + tid * 4;
  int v0 = (base + 0 < N) ? in[base + 0] : 0;
  int v1 = (base + 1 < N) ? in[base + 1] : 0;
  int v2 = (base + 2 < N) ? in[base + 2] : 0;
  int v3 = (base + 3 < N) ? in[base + 3] : 0;
  sd[tid] = v0 + v1 + v2 + v3;
  __syncthreads();
  for (int off = 1; off < 256; off <<= 1){
    int t = (tid >= off) ? sd[tid - off] : 0;
    __syncthreads();
    sd[tid] += t;
    __syncthreads();
  }
  int run = (tid > 0) ? sd[tid - 1] : 0;
  run += v0; if (base + 0 < N) out[base + 0] = run;
  run += v1; if (base + 1 < N) out[base + 1] = run;
  run += v2; if (base + 2 < N) out[base + 2] = run;
  run += v3; if (base + 3 < N) out[base + 3] = run;
  if (tid == 255) bsum[blockIdx.x] = sd[255];
}
__global__ void scan2_k(int* __restrict__ bs, int NB){
  __shared__ int sd[256];
  int tid = threadIdx.x;
  int base = tid * 4;
  int v0 = (base + 0 < NB) ? bs[base + 0] : 0;
  int v1 = (base + 1 < NB) ? bs[base + 1] : 0;
  int v2 = (base + 2 < NB) ? bs[base + 2] : 0;
  int v3 = (base + 3 < NB) ? bs[base + 3] : 0;
  sd[tid] = v0 + v1 + v2 + v3;
  __syncthreads();
  for (int off = 1; off < 256; off <<= 1){
    int t = (tid >= off) ? sd[tid - off] : 0;
    __syncthreads();
    sd[tid] += t;
    __syncthreads();
  }
  int run = (tid > 0) ? sd[tid - 1] : 0;
  run += v0; if (base + 0 < NB) bs[base + 0] = run;
  run += v1; if (base + 1 < NB) bs[base + 1] = run;
  run += v2; if (base + 2 < NB) bs[base + 2] = run;
  run += v3; if (base + 3 < NB) bs[base + 3] = run;
}
__global__ void scan3_k(int* __restrict__ out, const int* __restrict__ bsum, int N){
  int b = blockIdx.x;
  if (b == 0) return;
  int add = bsum[b - 1];
  int i = b * 1024 + threadIdx.x * 4;
  #pragma unroll
  for (int j = 0; j < 4; j++) if (i + j < N) out[i + j] += add;
}
__global__ void initfill_k(const int* __restrict__ incl, int* __restrict__ fill, int N){
  int i = blockIdx.x * 256 + threadIdx.x;
  if (i < N) fill[i] = (i == 0) ? 0 : incl[i - 1];
}
__global__ void fill_k(const int* __restrict__ dst, int* __restrict__ fill,
                       int* __restrict__ csr, int NE){
  int e = blockIdx.x * 256 + threadIdx.x;
  if (e < NE){
    int p = atomicAdd(&fill[dst[e]], 1);
    csr[p] = e;
  }
}

// ---------- fused GAT gather (bf16 X): online softmax + message + residual + LN ----------
__global__ __launch_bounds__(256) void gat_k(
    const int* __restrict__ incl, const int* __restrict__ csr,
    const int* __restrict__ src, const float* __restrict__ attr,
    const float* __restrict__ coeff, int ci,
    const float* __restrict__ as_, const float* __restrict__ ad_,
    const __hip_bfloat16* __restrict__ X, float* __restrict__ hout,
    const float* __restrict__ gb, const float* __restrict__ g,
    const float* __restrict__ b, __hip_bfloat16* __restrict__ xn,
    int M, int residual)
{
  int lane = threadIdx.x & 63, wid = threadIdx.x >> 6;
  int n = blockIdx.x * 4 + wid;
  if (n >= M) return;
  int beg = (n == 0) ? 0 : incl[n - 1];
  int end = incl[n];
  float c0 = 0.f, c1 = 0.f;
  if (attr){ c0 = coeff[ci]; c1 = coeff[NL + ci]; }
  float adn = ad_[n];
  float m = -1e30f, s = 0.f, acc0 = 0.f, acc1 = 0.f;
  for (int base = beg; base < end; base += 64){
    int idx = base + lane;
    bool valid = idx < end;
    int e = valid ? csr[idx] : 0;
    int sv = valid ? src[e] : 0;
    float a = -1e30f;
    if (valid){
      a = as_[sv] + adn;
      if (attr) a += attr[e] * c0 + c1;
      a = (a > 0.f) ? a : 0.2f * a;
    }
    float cm = wmax(a);
    float nm = fmaxf(m, cm);
    float sc = expf(m - nm);     // first chunk: exp(-1e30-x) -> 0
    acc0 *= sc; acc1 *= sc; s *= sc;
    float p = valid ? expf(a - nm) : 0.f;
    s += wsum(p);
    m = nm;
    int cnt = min(64, end - base);
    for (int t = 0; t < cnt; t++){
      float pt = __shfl(p, t, 64);
      int st = __shfl(sv, t, 64);
      unsigned u = *(const unsigned*)(X + (size_t)st * H + 2 * lane);
      acc0 += pt * __uint_as_float(u << 16);
      acc1 += pt * __uint_as_float(u & 0xffff0000u);
    }
  }
  float inv = (s == 0.f) ? 0.f : 1.f / s;
  acc0 *= inv; acc1 *= inv;
  int j0 = 2 * lane;
  if (residual){
    float2 hv = *(float2*)&hout[(size_t)n * H + j0];
    float2 gbv = *(const float2*)&gb[j0];
    hv.x += acc0 + gbv.x;
    hv.y += acc1 + gbv.y;
    *(float2*)&hout[(size_t)n * H + j0] = hv;
    float mu = wsum(hv.x + hv.y) * (1.f / H);
    float d0 = hv.x - mu, d1 = hv.y - mu;
    float var = wsum(d0 * d0 + d1 * d1) * (1.f / H);
    float rs = rsqrtf(var + 1e-5f);
    float2 gv = *(const float2*)&g[j0];
    float2 bv = *(const float2*)&b[j0];
    __hip_bfloat16 o0 = __float2bfloat16(d0 * rs * gv.x + bv.x);
    __hip_bfloat16 o1 = __float2bfloat16(d1 * rs * gv.y + bv.y);
    unsigned ow = ((unsigned)(*(unsigned short*)&o1) << 16) | (*(unsigned short*)&o0);
    *(unsigned*)((char*)xn + ((size_t)n * H + j0) * 2) = ow;
  } else {
    float2 o; o.x = acc0; o.y = acc1;
    *(float2*)&hout[(size_t)n * H + j0] = o;
  }
}

// ---------- final well MLP ----------
__global__ __launch_bounds__(128) void mlp_k(const float* __restrict__ hwell,
    const float* __restrict__ wb, const float* __restrict__ mW1,
    const float* __restrict__ mb1, const float* __restrict__ mW2,
    const float* __restrict__ mb2, float* __restrict__ out)
{
  __shared__ float sH[128], sT[128];
  int n = blockIdx.x, j = threadIdx.x;
  sH[j] = hwell[(size_t)n * H + j] + wb[j];
  __syncthreads();
  float a = mb1[j];
  for (int k = 0; k < 128; k++) a += sH[k] * mW1[k * 128 + j];
  sT[j] = fmaxf(a, 0.f);
  __syncthreads();
  if (j < 75){
    float o = mb2[j];
    for (int k = 0; k < 128; k++) o += sT[k] * mW2[k * 75 + j];
    out[(size_t)n * 75 + j] = o;
  }
}

extern "C" void kernel_launch(void* const* d_in, const int* in_sizes, int n_in,
                              void* d_out, int out_size, void* d_ws, size_t ws_size,
                              hipStream_t stream)
{
  (void)in_sizes; (void)n_in; (void)out_size; (void)ws_size;
  const float* cell_x = (const float*)d_in[0];
  const float* well_x = (const float*)d_in[1];
  const int*   eidx   = (const int*)d_in[2];
  const float* eattr  = (const float*)d_in[3];
  const int*   wsrc   = (const int*)d_in[4];
  const int*   wdst   = (const int*)d_in[5];
  const float* W_cell = (const float*)d_in[6];
  const float* b_cell = (const float*)d_in[7];
  const float* W_well = (const float*)d_in[8];
  const float* b_well = (const float*)d_in[9];
  const float* W_ee   = (const float*)d_in[10];
  const float* b_ee   = (const float*)d_in[11];
  const float* gW     = (const float*)d_in[12];
  const float* gas    = (const float*)d_in[13];
  const float* gad    = (const float*)d_in[14];
  const float* gae    = (const float*)d_in[15];
  const float* gWe    = (const float*)d_in[16];
  const float* gb     = (const float*)d_in[17];
  const float* n1g    = (const float*)d_in[18];
  const float* n1b    = (const float*)d_in[19];
  const float* fW1    = (const float*)d_in[20];
  const float* fb1    = (const float*)d_in[21];
  const float* fW2    = (const float*)d_in[22];
  const float* fb2    = (const float*)d_in[23];
  const float* n2g    = (const float*)d_in[24];
  const float* n2b    = (const float*)d_in[25];
  const float* wW     = (const float*)d_in[26];
  const float* was    = (const float*)d_in[27];
  const float* wad    = (const float*)d_in[28];
  const float* wb     = (const float*)d_in[29];
  const float* mW1    = (const float*)d_in[30];
  const float* mb1    = (const float*)d_in[31];
  const float* mW2    = (const float*)d_in[32];
  const float* mb2    = (const float*)d_in[33];

  const int* src = eidx;
  const int* dst = eidx + NE_CC;

  char* wsb = (char*)d_ws;
  size_t off = 0;
  auto alloc = [&](size_t bytes) -> void* {
    void* p = wsb + off; off += (bytes + 255) & ~(size_t)255; return p;
  };
  float* h      = (float*)alloc((size_t)NC * H * 4);
  __hip_bfloat16* xnbf = (__hip_bfloat16*)alloc((size_t)NC * H * 2);
  __hip_bfloat16* hsbf = (__hip_bfloat16*)alloc((size_t)NC * H * 2);
  float* as_    = (float*)alloc((size_t)NC * 4);
  float* ad_    = (float*)alloc((size_t)NC * 4);
  float* hw     = (float*)alloc((size_t)NW * H * 4);
  float* hwp    = (float*)alloc((size_t)NW * H * 4);
  float* hwell  = (float*)alloc((size_t)NW * H * 4);
  float* coeff  = (float*)alloc(64);
  __hip_bfloat16* gWT = (__hip_bfloat16*)alloc((size_t)NL * H * H * 2);
  __hip_bfloat16* W1T = (__hip_bfloat16*)alloc((size_t)NL * DFF * H * 2);
  __hip_bfloat16* W2T = (__hip_bfloat16*)alloc((size_t)NL * H * DFF * 2);
  __hip_bfloat16* wWT = (__hip_bfloat16*)alloc((size_t)H * H * 2);
  int* cntC  = (int*)alloc((size_t)NC * 4);
  int* inclC = (int*)alloc((size_t)NC * 4);
  int* fillC = (int*)alloc((size_t)NC * 4);
  int* csrC  = (int*)alloc((size_t)NE_CC * 4);
  int* inclW = (int*)alloc((size_t)NW * 4);
  int* fillW = (int*)alloc((size_t)NW * 4);
  int* csrW  = (int*)alloc((size_t)NE_CW * 4);
  int* bsum  = (int*)alloc(1024 * 4);

  const int eBlocks  = (NE_CC + 255) / 256;
  const int ewBlocks = (NE_CW + 255) / 256;
  const int NBC = (NC + 1023) / 1024;
  const int NBW = (NW + 1023) / 1024;

  // ---- CSR build (c2c) ----
  hipMemsetAsync(cntC, 0, (size_t)NC * 4, stream);
  count_k<<<eBlocks, 256, 0, stream>>>(dst, cntC, NE_CC);
  scan1_k<<<NBC, 256, 0, stream>>>(cntC, inclC, bsum, NC);
  scan2_k<<<1, 256, 0, stream>>>(bsum, NBC);
  scan3_k<<<NBC, 256, 0, stream>>>(inclC, bsum, NC);
  initfill_k<<<(NC + 255) / 256, 256, 0, stream>>>(inclC, fillC, NC);
  fill_k<<<eBlocks, 256, 0, stream>>>(dst, fillC, csrC, NE_CC);
  // ---- CSR build (c2w) ----
  hipMemsetAsync(fillW, 0, (size_t)NW * 4, stream);
  count_k<<<ewBlocks, 256, 0, stream>>>(wdst, fillW, NE_CW);
  scan1_k<<<NBW, 256, 0, stream>>>(fillW, inclW, bsum, NW);
  scan2_k<<<1, 256, 0, stream>>>(bsum, NBW);
  scan3_k<<<NBW, 256, 0, stream>>>(inclW, bsum, NW);
  initfill_k<<<(NW + 255) / 256, 256, 0, stream>>>(inclW, fillW, NW);
  fill_k<<<ewBlocks, 256, 0, stream>>>(wdst, fillW, csrW, NE_CW);

  // ---- weight prep ----
  prep_T_k<<<192, 256, 0, stream>>>(gW, gWT, 128, 128, NL);
  prep_T_k<<<768, 256, 0, stream>>>(fW1, W1T, 128, 512, NL);
  prep_T_k<<<768, 256, 0, stream>>>(fW2, W2T, 512, 128, NL);
  prep_T_k<<<64, 256, 0, stream>>>(wW, wWT, 128, 128, 1);

  embed_k<32><<<2048, 256, 0, stream>>>(cell_x, W_cell, b_cell, h, NC);
  embed_k<16><<<250, 256, 0, stream>>>(well_x, W_well, b_well, hw, NW);
  coeff_k<<<1, 128, 0, stream>>>(gWe, gae, W_ee, b_ee, coeff);

  const int lnBlocks = (NC + 3) / 4;
  const int mfmaBlocks = (NC + 127) / 128;

  ln_k<<<lnBlocks, 256, 0, stream>>>(h, n1g, n1b, xnbf, NC);  // layer-0 LN1

  for (int i = 0; i < NL; i++){
    gemm_mfma_k<<<mfmaBlocks, 512, 0, stream>>>(xnbf, gWT + (size_t)i * H * H,
        nullptr, hsbf, gas + i * H, gad + i * H, as_, ad_, NC);
    gat_k<<<lnBlocks, 256, 0, stream>>>(inclC, csrC, src, eattr, coeff, i,
        as_, ad_, hsbf, h, gb + i * H, n2g + i * H, n2b + i * H, xnbf, NC, 1);
    int last = (i == NL - 1);
    ffn_mfma_k<<<mfmaBlocks, 512, 0, stream>>>(xnbf, h,
        W1T + (size_t)i * DFF * H, fb1 + (size_t)i * DFF,
        W2T + (size_t)i * H * DFF, fb2 + (size_t)i * H,
        n1g + ((i + 1) % NL) * H, n1b + ((i + 1) % NL) * H,
        xnbf, last ? 1 : 0, NC);
  }

  // cell -> well bipartite GAT (xnbf now holds bf16(h))
  gemm_mfma_k<<<mfmaBlocks, 512, 0, stream>>>(xnbf, wWT,
      nullptr, hsbf, was, nullptr, as_, nullptr, NC);            // hc(bf16) + as_
  gemm128_k<<<(NW + 63) / 64, 256, 0, stream>>>(hw, wW, hwp, NW);
  dot2_k<<<(NW + 3) / 4, 256, 0, stream>>>(hwp, wad, ad_, NW);
  gat_k<<<(NW + 3) / 4, 256, 0, stream>>>(inclW, csrW, wsrc, nullptr, coeff, 0,
      as_, ad_, hsbf, hwell, nullptr, nullptr, nullptr, nullptr, NW, 0);
  mlp_k<<<NW, 128, 0, stream>>>(hwell, wb, mW1, mb1, mW2, mb2, (float*)d_out);
}

// Round 5
// 772.153 us; speedup vs baseline: 4.4357x; 1.0412x over previous
//
#include <hip/hip_runtime.h>
#include <hip/hip_bf16.h>

#define NC 100000
#define NW 500
#define NE_CC 600000
#define NE_CW 25000
#define H 128
#define NL 3
#define DFF 512
#define DC 64

typedef __bf16 bf16x8 __attribute__((ext_vector_type(8)));
typedef float f32x4 __attribute__((ext_vector_type(4)));
#define MFMA16(a,b,c) __builtin_amdgcn_mfma_f32_16x16x32_bf16(a,b,c,0,0,0)

__device__ __forceinline__ float wsum(float v){
  #pragma unroll
  for (int o = 32; o; o >>= 1) v += __shfl_xor(v, o, 64);
  return v;
}
__device__ __forceinline__ float wmax(float v){
  #pragma unroll
  for (int o = 32; o; o >>= 1) v = fmaxf(v, __shfl_xor(v, o, 64));
  return v;
}

// ---------- weight prep: out[l][n][k] = bf16(in[l][k][n]) ----------
__global__ void prep_T_k(const float* __restrict__ in, __hip_bfloat16* __restrict__ out,
                         int K, int N, int nmat)
{
  size_t tot = (size_t)nmat * K * N;
  for (size_t i = blockIdx.x * 256 + threadIdx.x; i < tot; i += (size_t)gridDim.x * 256){
    size_t l = i / ((size_t)K * N);
    size_t rem = i - l * (size_t)K * N;
    int n = (int)(rem / K), k = (int)(rem % K);
    out[i] = __float2bfloat16(in[l * (size_t)K * N + (size_t)k * N + n]);
  }
}

// ---------- embeddings ----------
template<int K>
__global__ __launch_bounds__(256) void embed_k(const float* __restrict__ x,
    const float* __restrict__ W, const float* __restrict__ b,
    float* __restrict__ h, int M)
{
  __shared__ float sW[K * 128];
  for (int t = threadIdx.x; t < K * 128; t += 256) sW[t] = W[t];
  __syncthreads();
  int j = threadIdx.x & 127, half = threadIdx.x >> 7;
  float bj = b[j];
  for (int n = blockIdx.x * 2 + half; n < M; n += gridDim.x * 2){
    const float* xr = x + (size_t)n * K;
    float acc = bj;
    #pragma unroll
    for (int k = 0; k < K; k++) acc += xr[k] * sW[k * 128 + j];
    h[(size_t)n * H + j] = acc;
  }
}

// ---------- per-layer scalar edge coefficients ----------
__global__ void coeff_k(const float* __restrict__ gWe, const float* __restrict__ gae,
    const float* __restrict__ Wee, const float* __restrict__ bee, float* __restrict__ coeff)
{
  __shared__ float red[4];
  int t = threadIdx.x;  // 0..127
  for (int i = 0; i < NL; i++){
    const float* Wr = gWe + ((size_t)i * H + t) * H;
    const float* ga = gae + (size_t)i * H;
    float w = 0.f;
    for (int k = 0; k < H; k++) w += Wr[k] * ga[k];
    float pc = Wee[t] * w, pd = bee[t] * w;
    pc = wsum(pc); pd = wsum(pd);
    if ((t & 63) == 0){ red[(t >> 6) * 2 + 0] = pc; red[(t >> 6) * 2 + 1] = pd; }
    __syncthreads();
    if (t == 0){ coeff[i] = red[0] + red[2]; coeff[NL + i] = red[1] + red[3]; }
    __syncthreads();
  }
}

// ---------- LayerNorm -> bf16 xn (used once, after embed) ----------
__global__ __launch_bounds__(256) void ln_k(const float* __restrict__ hin,
    const float* __restrict__ g, const float* __restrict__ b,
    __hip_bfloat16* __restrict__ xn, int M)
{
  int lane = threadIdx.x & 63, wid = threadIdx.x >> 6;
  int n = blockIdx.x * 4 + wid;
  if (n >= M) return;
  const float* row = hin + (size_t)n * H;
  float x0 = row[lane], x1 = row[lane + 64];
  float mu = wsum(x0 + x1) * (1.f / H);
  float d0 = x0 - mu, d1 = x1 - mu;
  float var = wsum(d0 * d0 + d1 * d1) * (1.f / H);
  float rs = rsqrtf(var + 1e-5f);
  xn[(size_t)n * H + lane]      = __float2bfloat16(d0 * rs * g[lane]      + b[lane]);
  xn[(size_t)n * H + lane + 64] = __float2bfloat16(d1 * rs * g[lane + 64] + b[lane + 64]);
}

// ---------- dot product per node (wells only) ----------
__global__ __launch_bounds__(256) void dot2_k(const float* __restrict__ X,
    const float* __restrict__ va, float* __restrict__ oa, int M)
{
  int lane = threadIdx.x & 63, wid = threadIdx.x >> 6;
  int n = blockIdx.x * 4 + wid;
  if (n >= M) return;
  const float* row = X + (size_t)n * H;
  float a = wsum(row[lane] * va[lane] + row[lane + 64] * va[lane + 64]);
  if (lane == 0) oa[n] = a;
}

// ---------- MFMA GEMM (+fused attention dots, optional fp32/bf16 C) ----------
__global__ __launch_bounds__(512, 4) void gemm_mfma_k(
    const __hip_bfloat16* __restrict__ A, const __hip_bfloat16* __restrict__ WT,
    float* __restrict__ C, __hip_bfloat16* __restrict__ Cbf,
    const float* __restrict__ va, const float* __restrict__ vb,
    float* __restrict__ oa, float* __restrict__ ob, int M)
{
  __shared__ __hip_bfloat16 sX[128 * 128];
  __shared__ __hip_bfloat16 sW[128 * 128];
  const int tid = threadIdx.x;
  const int lane = tid & 63, w = tid >> 6;
  const int n0 = blockIdx.x * 128;
  const int rw = w * 16;
  const int lr = lane & 15, lk = lane >> 4;

  for (int c = tid; c < 2048; c += 512){
    int r = c >> 4, s = c & 15;
    int row = n0 + r;
    uint4 v = make_uint4(0u, 0u, 0u, 0u);
    if (row < M) v = *(const uint4*)(A + (size_t)row * 128 + s * 8);
    *(uint4*)((char*)sX + r * 256 + ((s * 16) ^ ((r & 7) << 4))) = v;
  }
  for (int c = tid; c < 2048; c += 512){
    int r = c >> 4, s = c & 15;
    uint4 v = *(const uint4*)(WT + (size_t)r * 128 + s * 8);
    *(uint4*)((char*)sW + r * 256 + ((s * 16) ^ ((r & 7) << 4))) = v;
  }
  __syncthreads();

  f32x4 acc[8];
  #pragma unroll
  for (int i = 0; i < 8; i++) acc[i] = (f32x4){0.f, 0.f, 0.f, 0.f};
  #pragma unroll
  for (int ks = 0; ks < 4; ks++){
    int arow = rw + lr;
    int ak = ks * 32 + lk * 8;
    bf16x8 a = *(const bf16x8*)((const char*)sX + arow * 256 + ((ak * 2) ^ ((arow & 7) << 4)));
    #pragma unroll
    for (int nt = 0; nt < 8; nt++){
      int brow = nt * 16 + lr;
      bf16x8 b = *(const bf16x8*)((const char*)sW + brow * 256 + ((ak * 2) ^ ((brow & 7) << 4)));
      acc[nt] = MFMA16(a, b, acc[nt]);
    }
  }
  #pragma unroll
  for (int nt = 0; nt < 8; nt++){
    int col = nt * 16 + lr;
    #pragma unroll
    for (int r = 0; r < 4; r++){
      int row = n0 + rw + lk * 4 + r;
      if (row < M){
        if (C)   C[(size_t)row * 128 + col] = acc[nt][r];
        if (Cbf) Cbf[(size_t)row * 128 + col] = __float2bfloat16(acc[nt][r]);
      }
    }
  }
  if (va){
    float vac[8], vbc[8];
    #pragma unroll
    for (int nt = 0; nt < 8; nt++){
      vac[nt] = va[nt * 16 + lr];
      vbc[nt] = vb ? vb[nt * 16 + lr] : 0.f;
    }
    #pragma unroll
    for (int r = 0; r < 4; r++){
      float da = 0.f, db = 0.f;
      #pragma unroll
      for (int nt = 0; nt < 8; nt++){
        da += acc[nt][r] * vac[nt];
        db += acc[nt][r] * vbc[nt];
      }
      #pragma unroll
      for (int o = 1; o < 16; o <<= 1){
        da += __shfl_xor(da, o, 64);
        db += __shfl_xor(db, o, 64);
      }
      int row = n0 + rw + lk * 4 + r;
      if (lr == 0 && row < M){
        oa[row] = da;
        if (ob) ob[row] = db;
      }
    }
  }
}

// ---------- MFMA fused FFN: h += relu(xn@W1+b1)@W2 + b2, epilogue LN or bf16 ----------
__global__ __launch_bounds__(512, 4) void ffn_mfma_k(
    const __hip_bfloat16* __restrict__ xn, float* __restrict__ h,
    const __hip_bfloat16* __restrict__ W1T, const float* __restrict__ b1,
    const __hip_bfloat16* __restrict__ W2T, const float* __restrict__ b2,
    const float* __restrict__ lng, const float* __restrict__ lnb,
    __hip_bfloat16* __restrict__ xout, int mode, int M)   // mode 0: LN->xout, 1: bf16->xout
{
  __shared__ __hip_bfloat16 sX[128 * 128];
  __shared__ __hip_bfloat16 sW1[DC * 128];
  __shared__ __hip_bfloat16 sW2[128 * DC];
  __shared__ __hip_bfloat16 sT[128 * DC];
  const int tid = threadIdx.x;
  const int lane = tid & 63, w = tid >> 6;
  const int n0 = blockIdx.x * 128;
  const int rw = w * 16;
  const int lr = lane & 15, lk = lane >> 4;

  for (int c = tid; c < 2048; c += 512){
    int r = c >> 4, s = c & 15;
    int row = n0 + r;
    uint4 v = make_uint4(0u, 0u, 0u, 0u);
    if (row < M) v = *(const uint4*)(xn + (size_t)row * 128 + s * 8);
    *(uint4*)((char*)sX + r * 256 + ((s * 16) ^ ((r & 7) << 4))) = v;
  }

  f32x4 acc2[8];
  #pragma unroll
  for (int i = 0; i < 8; i++) acc2[i] = (f32x4){0.f, 0.f, 0.f, 0.f};

  for (int ch = 0; ch < DFF / DC; ch++){
    __syncthreads();
    for (int c = tid; c < 1024; c += 512){
      int r = c >> 4, s = c & 15;
      uint4 v = *(const uint4*)(W1T + (size_t)(ch * DC + r) * 128 + s * 8);
      *(uint4*)((char*)sW1 + r * 256 + ((s * 16) ^ ((r & 7) << 4))) = v;
    }
    for (int c = tid; c < 1024; c += 512){
      int r = c >> 3, s = c & 7;
      uint4 v = *(const uint4*)(W2T + (size_t)r * DFF + ch * DC + s * 8);
      *(uint4*)((char*)sW2 + r * 128 + ((s * 16) ^ ((r & 7) << 4))) = v;
    }
    __syncthreads();

    f32x4 acc1[4];
    #pragma unroll
    for (int i = 0; i < 4; i++) acc1[i] = (f32x4){0.f, 0.f, 0.f, 0.f};
    #pragma unroll
    for (int ks = 0; ks < 4; ks++){
      int arow = rw + lr;
      int ak = ks * 32 + lk * 8;
      bf16x8 a = *(const bf16x8*)((const char*)sX + arow * 256 + ((ak * 2) ^ ((arow & 7) << 4)));
      #pragma unroll
      for (int nt = 0; nt < 4; nt++){
        int brow = nt * 16 + lr;
        bf16x8 b = *(const bf16x8*)((const char*)sW1 + brow * 256 + ((ak * 2) ^ ((brow & 7) << 4)));
        acc1[nt] = MFMA16(a, b, acc1[nt]);
      }
    }
    #pragma unroll
    for (int nt = 0; nt < 4; nt++){
      int col = nt * 16 + lr;
      float bb = b1[ch * DC + col];
      #pragma unroll
      for (int r = 0; r < 4; r++){
        int row = rw + lk * 4 + r;
        float v = fmaxf(acc1[nt][r] + bb, 0.f);
        *(__hip_bfloat16*)((char*)sT + row * 128 + ((col * 2) ^ ((row & 7) << 4))) =
            __float2bfloat16(v);
      }
    }
    asm volatile("s_waitcnt lgkmcnt(0)" ::: "memory");

    #pragma unroll
    for (int ks = 0; ks < 2; ks++){
      int arow = rw + lr;
      int ak = ks * 32 + lk * 8;
      bf16x8 a = *(const bf16x8*)((const char*)sT + arow * 128 + ((ak * 2) ^ ((arow & 7) << 4)));
      #pragma unroll
      for (int nt = 0; nt < 8; nt++){
        int brow = nt * 16 + lr;
        bf16x8 b = *(const bf16x8*)((const char*)sW2 + brow * 128 + ((ak * 2) ^ ((brow & 7) << 4)));
        acc2[nt] = MFMA16(a, b, acc2[nt]);
      }
    }
  }

  float b2c[8];
  #pragma unroll
  for (int nt = 0; nt < 8; nt++) b2c[nt] = b2[nt * 16 + lr];

  #pragma unroll
  for (int r = 0; r < 4; r++){
    int row = n0 + rw + lk * 4 + r;
    bool ok = row < M;
    float val[8]; float sum = 0.f;
    #pragma unroll
    for (int nt = 0; nt < 8; nt++){
      int col = nt * 16 + lr;
      float hv = ok ? h[(size_t)row * 128 + col] : 0.f;
      val[nt] = hv + acc2[nt][r] + b2c[nt];
      sum += val[nt];
    }
    if (mode == 0){
      #pragma unroll
      for (int o = 1; o < 16; o <<= 1) sum += __shfl_xor(sum, o, 64);
      float mu = sum * (1.f / 128.f);
      float vs = 0.f;
      #pragma unroll
      for (int nt = 0; nt < 8; nt++){ float d = val[nt] - mu; vs += d * d; }
      #pragma unroll
      for (int o = 1; o < 16; o <<= 1) vs += __shfl_xor(vs, o, 64);
      float rs = rsqrtf(vs * (1.f / 128.f) + 1e-5f);
      #pragma unroll
      for (int nt = 0; nt < 8; nt++){
        int col = nt * 16 + lr;
        if (ok){
          h[(size_t)row * 128 + col] = val[nt];
          xout[(size_t)row * 128 + col] =
              __float2bfloat16((val[nt] - mu) * rs * lng[col] + lnb[col]);
        }
      }
    } else {
      #pragma unroll
      for (int nt = 0; nt < 8; nt++){
        int col = nt * 16 + lr;
        if (ok){
          h[(size_t)row * 128 + col] = val[nt];
          xout[(size_t)row * 128 + col] = __float2bfloat16(val[nt]);
        }
      }
    }
  }
}

// ---------- fp32 GEMM (tiny well matmul) ----------
__global__ __launch_bounds__(256) void gemm128_k(const float* __restrict__ A,
    const float* __restrict__ Bm, float* __restrict__ C, int M)
{
  __shared__ float sB[32 * 128];
  __shared__ float sA[64 * 33];
  const int tid = threadIdx.x;
  const int n0 = blockIdx.x * 64;
  const int j4 = (tid & 31) * 4;
  const int rB = (tid >> 5) * 8;
  float acc[8][4];
  #pragma unroll
  for (int r = 0; r < 8; r++){ acc[r][0]=acc[r][1]=acc[r][2]=acc[r][3]=0.f; }
  for (int kc = 0; kc < 128; kc += 32){
    for (int t = tid; t < 4096; t += 256){
      int kk = t >> 7, j = t & 127;
      sB[kk * 128 + j] = Bm[(size_t)(kc + kk) * H + j];
    }
    for (int t = tid; t < 2048; t += 256){
      int n = t >> 5, kk = t & 31; int row = n0 + n;
      sA[n * 33 + kk] = (row < M) ? A[(size_t)row * H + kc + kk] : 0.f;
    }
    __syncthreads();
    #pragma unroll 8
    for (int kk = 0; kk < 32; kk++){
      float4 bv = *(const float4*)&sB[kk * 128 + j4];
      #pragma unroll
      for (int r = 0; r < 8; r++){
        float av = sA[(rB + r) * 33 + kk];
        acc[r][0] += av * bv.x; acc[r][1] += av * bv.y;
        acc[r][2] += av * bv.z; acc[r][3] += av * bv.w;
      }
    }
    __syncthreads();
  }
  #pragma unroll
  for (int r = 0; r < 8; r++){
    int row = n0 + rB + r;
    if (row < M){
      float4 o; o.x = acc[r][0]; o.y = acc[r][1]; o.z = acc[r][2]; o.w = acc[r][3];
      *(float4*)&C[(size_t)row * H + j4] = o;
    }
  }
}

// ---------- CSR build ----------
__global__ void count_k(const int* __restrict__ dst, int* __restrict__ cnt, int NE){
  int e = blockIdx.x * 256 + threadIdx.x;
  if (e < NE) atomicAdd(&cnt[dst[e]], 1);
}
__global__ void scan1_k(const int* __restrict__ in, int* __restrict__ out,
                        int* __restrict__ bsum, int N){
  __shared__ int sd[256];
  int tid = threadIdx.x;
  int base = blockIdx.x * 1024 + tid * 4;
  int v0 = (base + 0 < N) ? in[base + 0] : 0;
  int v1 = (base + 1 < N) ? in[base + 1] : 0;
  int v2 = (base + 2 < N) ? in[base + 2] : 0;
  int v3 = (base + 3 < N) ? in[base + 3] : 0;
  sd[tid] = v0 + v1 + v2 + v3;
  __syncthreads();
  for (int off = 1; off < 256; off <<= 1){
    int t = (tid >= off) ? sd[tid - off] : 0;
    __syncthreads();
    sd[tid] += t;
    __syncthreads();
  }
  int run = (tid > 0) ? sd[tid - 1] : 0;
  run += v0; if (base + 0 < N) out[base + 0] = run;
  run += v1; if (base + 1 < N) out[base + 1] = run;
  run += v2; if (base + 2 < N) out[base + 2] = run;
  run += v3; if (base + 3 < N) out[base + 3] = run;
  if (tid == 255) bsum[blockIdx.x] = sd[255];
}
__global__ void scan2_k(int* __restrict__ bs, int NB){
  __shared__ int sd[256];
  int tid = threadIdx.x;
  int base = tid * 4;
  int v0 = (base + 0 < NB) ? bs[base + 0] : 0;
  int v1 = (base + 1 < NB) ? bs[base + 1] : 0;
  int v2 = (base + 2 < NB) ? bs[base + 2] : 0;
  int v3 = (base + 3 < NB) ? bs[base + 3] : 0;
  sd[tid] = v0 + v1 + v2 + v3;
  __syncthreads();
  for (int off = 1; off < 256; off <<= 1){
    int t = (tid >= off) ? sd[tid - off] : 0;
    __syncthreads();
    sd[tid] += t;
    __syncthreads();
  }
  int run = (tid > 0) ? sd[tid - 1] : 0;
  run += v0; if (base + 0 < NB) bs[base + 0] = run;
  run += v1; if (base + 1 < NB) bs[base + 1] = run;
  run += v2; if (base + 2 < NB) bs[base + 2] = run;
  run += v3; if (base + 3 < NB) bs[base + 3] = run;
}
__global__ void scan3_k(int* __restrict__ out, const int* __restrict__ bsum, int N){
  int b = blockIdx.x;
  if (b == 0) return;
  int add = bsum[b - 1];
  int i = b * 1024 + threadIdx.x * 4;
  #pragma unroll
  for (int j = 0; j < 4; j++) if (i + j < N) out[i + j] += add;
}
__global__ void initfill_k(const int* __restrict__ incl, int* __restrict__ fill, int N){
  int i = blockIdx.x * 256 + threadIdx.x;
  if (i < N) fill[i] = (i == 0) ? 0 : incl[i - 1];
}
__global__ void fill_k(const int* __restrict__ dst, int* __restrict__ fill,
                       int* __restrict__ csr, int NE){
  int e = blockIdx.x * 256 + threadIdx.x;
  if (e < NE){
    int p = atomicAdd(&fill[dst[e]], 1);
    csr[p] = e;
  }
}

// ---------- fused GAT gather (bf16 X, 4-edge-parallel): softmax + msg + residual + LN ----------
__global__ __launch_bounds__(256) void gat_k(
    const int* __restrict__ incl, const int* __restrict__ csr,
    const int* __restrict__ src, const float* __restrict__ attr,
    const float* __restrict__ coeff, int ci,
    const float* __restrict__ as_, const float* __restrict__ ad_,
    const __hip_bfloat16* __restrict__ X, float* __restrict__ hout,
    const float* __restrict__ gb, const float* __restrict__ g,
    const float* __restrict__ b, __hip_bfloat16* __restrict__ xn,
    int M, int residual)
{
  int lane = threadIdx.x & 63, wid = threadIdx.x >> 6;
  int n = blockIdx.x * 4 + wid;
  if (n >= M) return;
  int beg = (n == 0) ? 0 : incl[n - 1];
  int end = incl[n];
  float c0 = 0.f, c1 = 0.f;
  if (attr){ c0 = coeff[ci]; c1 = coeff[NL + ci]; }
  float adn = ad_[n];
  const int grp = lane >> 4;      // edge slot 0..3
  const int dblk = lane & 15;     // dim block (8 dims)
  float m = -1e30f, s = 0.f;
  float acc[8];
  #pragma unroll
  for (int i = 0; i < 8; i++) acc[i] = 0.f;

  for (int base = beg; base < end; base += 64){
    int idx = base + lane;
    bool valid = idx < end;
    int e = valid ? csr[idx] : 0;
    int sv = valid ? src[e] : 0;
    float a = -1e30f;
    if (valid){
      a = as_[sv] + adn;
      if (attr) a += attr[e] * c0 + c1;
      a = (a > 0.f) ? a : 0.2f * a;
    }
    float cm = wmax(a);
    float nm = fmaxf(m, cm);
    float sc = expf(m - nm);     // first chunk: exp(-1e30-x) -> 0
    #pragma unroll
    for (int i = 0; i < 8; i++) acc[i] *= sc;
    s *= sc;
    float p = valid ? expf(a - nm) : 0.f;
    s += wsum(p);
    m = nm;
    int cnt = min(64, end - base);
    for (int t = 0; t < cnt; t += 4){
      int tt = t + grp;
      float pt = __shfl(p, tt, 64);
      int st = __shfl(sv, tt, 64);
      if (tt < cnt){
        uint4 u = *(const uint4*)(X + (size_t)st * H + dblk * 8);
        acc[0] += pt * __uint_as_float(u.x << 16);
        acc[1] += pt * __uint_as_float(u.x & 0xffff0000u);
        acc[2] += pt * __uint_as_float(u.y << 16);
        acc[3] += pt * __uint_as_float(u.y & 0xffff0000u);
        acc[4] += pt * __uint_as_float(u.z << 16);
        acc[5] += pt * __uint_as_float(u.z & 0xffff0000u);
        acc[6] += pt * __uint_as_float(u.w << 16);
        acc[7] += pt * __uint_as_float(u.w & 0xffff0000u);
      }
    }
  }
  // cross-group reduction: lanes {l, l^16, l^32, l^48} hold partial sums of same dims
  #pragma unroll
  for (int i = 0; i < 8; i++){
    acc[i] += __shfl_xor(acc[i], 16, 64);
    acc[i] += __shfl_xor(acc[i], 32, 64);
  }
  float inv = (s == 0.f) ? 0.f : 1.f / s;
  int j0 = dblk * 8;
  if (residual){
    float hv[8]; float localsum = 0.f;
    if (grp == 0){
      float4 h0 = *(float4*)&hout[(size_t)n * H + j0];
      float4 h1 = *(float4*)&hout[(size_t)n * H + j0 + 4];
      float4 g0 = *(const float4*)&gb[j0];
      float4 g1 = *(const float4*)&gb[j0 + 4];
      hv[0] = h0.x + acc[0] * inv + g0.x; hv[1] = h0.y + acc[1] * inv + g0.y;
      hv[2] = h0.z + acc[2] * inv + g0.z; hv[3] = h0.w + acc[3] * inv + g0.w;
      hv[4] = h1.x + acc[4] * inv + g1.x; hv[5] = h1.y + acc[5] * inv + g1.y;
      hv[6] = h1.z + acc[6] * inv + g1.z; hv[7] = h1.w + acc[7] * inv + g1.w;
      #pragma unroll
      for (int i = 0; i < 8; i++) localsum += hv[i];
    }
    float mu = wsum(grp == 0 ? localsum : 0.f) * (1.f / H);
    float vs = 0.f;
    if (grp == 0){
      #pragma unroll
      for (int i = 0; i < 8; i++){ float d = hv[i] - mu; vs += d * d; }
    }
    float var = wsum(grp == 0 ? vs : 0.f) * (1.f / H);
    float rs = rsqrtf(var + 1e-5f);
    if (grp == 0){
      float4 o0, o1;
      o0.x = hv[0]; o0.y = hv[1]; o0.z = hv[2]; o0.w = hv[3];
      o1.x = hv[4]; o1.y = hv[5]; o1.z = hv[6]; o1.w = hv[7];
      *(float4*)&hout[(size_t)n * H + j0] = o0;
      *(float4*)&hout[(size_t)n * H + j0 + 4] = o1;
      float4 gg0 = *(const float4*)&g[j0];
      float4 gg1 = *(const float4*)&g[j0 + 4];
      float4 bb0 = *(const float4*)&b[j0];
      float4 bb1 = *(const float4*)&b[j0 + 4];
      float xo[8];
      xo[0] = (hv[0]-mu)*rs*gg0.x + bb0.x; xo[1] = (hv[1]-mu)*rs*gg0.y + bb0.y;
      xo[2] = (hv[2]-mu)*rs*gg0.z + bb0.z; xo[3] = (hv[3]-mu)*rs*gg0.w + bb0.w;
      xo[4] = (hv[4]-mu)*rs*gg1.x + bb1.x; xo[5] = (hv[5]-mu)*rs*gg1.y + bb1.y;
      xo[6] = (hv[6]-mu)*rs*gg1.z + bb1.z; xo[7] = (hv[7]-mu)*rs*gg1.w + bb1.w;
      uint4 ow;
      unsigned* owp = (unsigned*)&ow;
      #pragma unroll
      for (int i = 0; i < 4; i++){
        __hip_bfloat16 lo = __float2bfloat16(xo[2*i]);
        __hip_bfloat16 hi = __float2bfloat16(xo[2*i+1]);
        owp[i] = ((unsigned)(*(unsigned short*)&hi) << 16) | (*(unsigned short*)&lo);
      }
      *(uint4*)((char*)xn + ((size_t)n * H + j0) * 2) = ow;
    }
  } else {
    if (grp == 0){
      float4 o0, o1;
      o0.x = acc[0]*inv; o0.y = acc[1]*inv; o0.z = acc[2]*inv; o0.w = acc[3]*inv;
      o1.x = acc[4]*inv; o1.y = acc[5]*inv; o1.z = acc[6]*inv; o1.w = acc[7]*inv;
      *(float4*)&hout[(size_t)n * H + j0] = o0;
      *(float4*)&hout[(size_t)n * H + j0 + 4] = o1;
    }
  }
}

// ---------- final well MLP ----------
__global__ __launch_bounds__(128) void mlp_k(const float* __restrict__ hwell,
    const float* __restrict__ wb, const float* __restrict__ mW1,
    const float* __restrict__ mb1, const float* __restrict__ mW2,
    const float* __restrict__ mb2, float* __restrict__ out)
{
  __shared__ float sH[128], sT[128];
  int n = blockIdx.x, j = threadIdx.x;
  sH[j] = hwell[(size_t)n * H + j] + wb[j];
  __syncthreads();
  float a = mb1[j];
  for (int k = 0; k < 128; k++) a += sH[k] * mW1[k * 128 + j];
  sT[j] = fmaxf(a, 0.f);
  __syncthreads();
  if (j < 75){
    float o = mb2[j];
    for (int k = 0; k < 128; k++) o += sT[k] * mW2[k * 75 + j];
    out[(size_t)n * 75 + j] = o;
  }
}

extern "C" void kernel_launch(void* const* d_in, const int* in_sizes, int n_in,
                              void* d_out, int out_size, void* d_ws, size_t ws_size,
                              hipStream_t stream)
{
  (void)in_sizes; (void)n_in; (void)out_size; (void)ws_size;
  const float* cell_x = (const float*)d_in[0];
  const float* well_x = (const float*)d_in[1];
  const int*   eidx   = (const int*)d_in[2];
  const float* eattr  = (const float*)d_in[3];
  const int*   wsrc   = (const int*)d_in[4];
  const int*   wdst   = (const int*)d_in[5];
  const float* W_cell = (const float*)d_in[6];
  const float* b_cell = (const float*)d_in[7];
  const float* W_well = (const float*)d_in[8];
  const float* b_well = (const float*)d_in[9];
  const float* W_ee   = (const float*)d_in[10];
  const float* b_ee   = (const float*)d_in[11];
  const float* gW     = (const float*)d_in[12];
  const float* gas    = (const float*)d_in[13];
  const float* gad    = (const float*)d_in[14];
  const float* gae    = (const float*)d_in[15];
  const float* gWe    = (const float*)d_in[16];
  const float* gb     = (const float*)d_in[17];
  const float* n1g    = (const float*)d_in[18];
  const float* n1b    = (const float*)d_in[19];
  const float* fW1    = (const float*)d_in[20];
  const float* fb1    = (const float*)d_in[21];
  const float* fW2    = (const float*)d_in[22];
  const float* fb2    = (const float*)d_in[23];
  const float* n2g    = (const float*)d_in[24];
  const float* n2b    = (const float*)d_in[25];
  const float* wW     = (const float*)d_in[26];
  const float* was    = (const float*)d_in[27];
  const float* wad    = (const float*)d_in[28];
  const float* wb     = (const float*)d_in[29];
  const float* mW1    = (const float*)d_in[30];
  const float* mb1    = (const float*)d_in[31];
  const float* mW2    = (const float*)d_in[32];
  const float* mb2    = (const float*)d_in[33];

  const int* src = eidx;
  const int* dst = eidx + NE_CC;

  char* wsb = (char*)d_ws;
  size_t off = 0;
  auto alloc = [&](size_t bytes) -> void* {
    void* p = wsb + off; off += (bytes + 255) & ~(size_t)255; return p;
  };
  float* h      = (float*)alloc((size_t)NC * H * 4);
  __hip_bfloat16* xnbf = (__hip_bfloat16*)alloc((size_t)NC * H * 2);
  __hip_bfloat16* hsbf = (__hip_bfloat16*)alloc((size_t)NC * H * 2);
  float* as_    = (float*)alloc((size_t)NC * 4);
  float* ad_    = (float*)alloc((size_t)NC * 4);
  float* hw     = (float*)alloc((size_t)NW * H * 4);
  float* hwp    = (float*)alloc((size_t)NW * H * 4);
  float* hwell  = (float*)alloc((size_t)NW * H * 4);
  float* coeff  = (float*)alloc(64);
  __hip_bfloat16* gWT = (__hip_bfloat16*)alloc((size_t)NL * H * H * 2);
  __hip_bfloat16* W1T = (__hip_bfloat16*)alloc((size_t)NL * DFF * H * 2);
  __hip_bfloat16* W2T = (__hip_bfloat16*)alloc((size_t)NL * H * DFF * 2);
  __hip_bfloat16* wWT = (__hip_bfloat16*)alloc((size_t)H * H * 2);
  int* cntC  = (int*)alloc((size_t)NC * 4);
  int* inclC = (int*)alloc((size_t)NC * 4);
  int* fillC = (int*)alloc((size_t)NC * 4);
  int* csrC  = (int*)alloc((size_t)NE_CC * 4);
  int* inclW = (int*)alloc((size_t)NW * 4);
  int* fillW = (int*)alloc((size_t)NW * 4);
  int* csrW  = (int*)alloc((size_t)NE_CW * 4);
  int* bsum  = (int*)alloc(1024 * 4);

  const int eBlocks  = (NE_CC + 255) / 256;
  const int ewBlocks = (NE_CW + 255) / 256;
  const int NBC = (NC + 1023) / 1024;
  const int NBW = (NW + 1023) / 1024;

  // ---- CSR build (c2c) ----
  hipMemsetAsync(cntC, 0, (size_t)NC * 4, stream);
  count_k<<<eBlocks, 256, 0, stream>>>(dst, cntC, NE_CC);
  scan1_k<<<NBC, 256, 0, stream>>>(cntC, inclC, bsum, NC);
  scan2_k<<<1, 256, 0, stream>>>(bsum, NBC);
  scan3_k<<<NBC, 256, 0, stream>>>(inclC, bsum, NC);
  initfill_k<<<(NC + 255) / 256, 256, 0, stream>>>(inclC, fillC, NC);
  fill_k<<<eBlocks, 256, 0, stream>>>(dst, fillC, csrC, NE_CC);
  // ---- CSR build (c2w) ----
  hipMemsetAsync(fillW, 0, (size_t)NW * 4, stream);
  count_k<<<ewBlocks, 256, 0, stream>>>(wdst, fillW, NE_CW);
  scan1_k<<<NBW, 256, 0, stream>>>(fillW, inclW, bsum, NW);
  scan2_k<<<1, 256, 0, stream>>>(bsum, NBW);
  scan3_k<<<NBW, 256, 0, stream>>>(inclW, bsum, NW);
  initfill_k<<<(NW + 255) / 256, 256, 0, stream>>>(inclW, fillW, NW);
  fill_k<<<ewBlocks, 256, 0, stream>>>(wdst, fillW, csrW, NE_CW);

  // ---- weight prep ----
  prep_T_k<<<192, 256, 0, stream>>>(gW, gWT, 128, 128, NL);
  prep_T_k<<<768, 256, 0, stream>>>(fW1, W1T, 128, 512, NL);
  prep_T_k<<<768, 256, 0, stream>>>(fW2, W2T, 512, 128, NL);
  prep_T_k<<<64, 256, 0, stream>>>(wW, wWT, 128, 128, 1);

  embed_k<32><<<2048, 256, 0, stream>>>(cell_x, W_cell, b_cell, h, NC);
  embed_k<16><<<250, 256, 0, stream>>>(well_x, W_well, b_well, hw, NW);
  coeff_k<<<1, 128, 0, stream>>>(gWe, gae, W_ee, b_ee, coeff);

  const int lnBlocks = (NC + 3) / 4;
  const int mfmaBlocks = (NC + 127) / 128;

  ln_k<<<lnBlocks, 256, 0, stream>>>(h, n1g, n1b, xnbf, NC);  // layer-0 LN1

  for (int i = 0; i < NL; i++){
    gemm_mfma_k<<<mfmaBlocks, 512, 0, stream>>>(xnbf, gWT + (size_t)i * H * H,
        nullptr, hsbf, gas + i * H, gad + i * H, as_, ad_, NC);
    gat_k<<<lnBlocks, 256, 0, stream>>>(inclC, csrC, src, eattr, coeff, i,
        as_, ad_, hsbf, h, gb + i * H, n2g + i * H, n2b + i * H, xnbf, NC, 1);
    int last = (i == NL - 1);
    ffn_mfma_k<<<mfmaBlocks, 512, 0, stream>>>(xnbf, h,
        W1T + (size_t)i * DFF * H, fb1 + (size_t)i * DFF,
        W2T + (size_t)i * H * DFF, fb2 + (size_t)i * H,
        n1g + ((i + 1) % NL) * H, n1b + ((i + 1) % NL) * H,
        xnbf, last ? 1 : 0, NC);
  }

  // cell -> well bipartite GAT (xnbf now holds bf16(h))
  gemm_mfma_k<<<mfmaBlocks, 512, 0, stream>>>(xnbf, wWT,
      nullptr, hsbf, was, nullptr, as_, nullptr, NC);            // hc(bf16) + as_
  gemm128_k<<<(NW + 63) / 64, 256, 0, stream>>>(hw, wW, hwp, NW);
  dot2_k<<<(NW + 3) / 4, 256, 0, stream>>>(hwp, wad, ad_, NW);
  gat_k<<<(NW + 3) / 4, 256, 0, stream>>>(inclW, csrW, wsrc, nullptr, coeff, 0,
      as_, ad_, hsbf, hwell, nullptr, nullptr, nullptr, nullptr, NW, 0);
  mlp_k<<<NW, 128, 0, stream>>>(hwell, wb, mW1, mb1, mW2, mb2, (float*)d_out);
}

// Round 6
// 732.288 us; speedup vs baseline: 4.6772x; 1.0544x over previous
//
#include <hip/hip_runtime.h>
#include <hip/hip_bf16.h>

#define NC 100000
#define NW 500
#define NE_CC 600000
#define NE_CW 25000
#define H 128
#define NL 3
#define DFF 512
#define DC 64

typedef __bf16 bf16x8 __attribute__((ext_vector_type(8)));
typedef float f32x4 __attribute__((ext_vector_type(4)));
#define MFMA16(a,b,c) __builtin_amdgcn_mfma_f32_16x16x32_bf16(a,b,c,0,0,0)

__device__ __forceinline__ float wsum(float v){
  #pragma unroll
  for (int o = 32; o; o >>= 1) v += __shfl_xor(v, o, 64);
  return v;
}
__device__ __forceinline__ float gsum16(float v){
  #pragma unroll
  for (int o = 1; o < 16; o <<= 1) v += __shfl_xor(v, o, 64);
  return v;
}
__device__ __forceinline__ float gmax16(float v){
  #pragma unroll
  for (int o = 1; o < 16; o <<= 1) v = fmaxf(v, __shfl_xor(v, o, 64));
  return v;
}

// ---------- weight prep: out[l][n][k] = bf16(in[l][k][n]) ----------
__global__ void prep_T_k(const float* __restrict__ in, __hip_bfloat16* __restrict__ out,
                         int K, int N, int nmat)
{
  size_t tot = (size_t)nmat * K * N;
  for (size_t i = blockIdx.x * 256 + threadIdx.x; i < tot; i += (size_t)gridDim.x * 256){
    size_t l = i / ((size_t)K * N);
    size_t rem = i - l * (size_t)K * N;
    int n = (int)(rem / K), k = (int)(rem % K);
    out[i] = __float2bfloat16(in[l * (size_t)K * N + (size_t)k * N + n]);
  }
}

// ---------- embeddings ----------
template<int K>
__global__ __launch_bounds__(256) void embed_k(const float* __restrict__ x,
    const float* __restrict__ W, const float* __restrict__ b,
    float* __restrict__ h, int M)
{
  __shared__ float sW[K * 128];
  for (int t = threadIdx.x; t < K * 128; t += 256) sW[t] = W[t];
  __syncthreads();
  int j = threadIdx.x & 127, half = threadIdx.x >> 7;
  float bj = b[j];
  for (int n = blockIdx.x * 2 + half; n < M; n += gridDim.x * 2){
    const float* xr = x + (size_t)n * K;
    float acc = bj;
    #pragma unroll
    for (int k = 0; k < K; k++) acc += xr[k] * sW[k * 128 + j];
    h[(size_t)n * H + j] = acc;
  }
}

// ---------- per-layer scalar edge coefficients ----------
__global__ void coeff_k(const float* __restrict__ gWe, const float* __restrict__ gae,
    const float* __restrict__ Wee, const float* __restrict__ bee, float* __restrict__ coeff)
{
  __shared__ float red[4];
  int t = threadIdx.x;  // 0..127
  for (int i = 0; i < NL; i++){
    const float* Wr = gWe + ((size_t)i * H + t) * H;
    const float* ga = gae + (size_t)i * H;
    float w = 0.f;
    for (int k = 0; k < H; k++) w += Wr[k] * ga[k];
    float pc = Wee[t] * w, pd = bee[t] * w;
    pc = wsum(pc); pd = wsum(pd);
    if ((t & 63) == 0){ red[(t >> 6) * 2 + 0] = pc; red[(t >> 6) * 2 + 1] = pd; }
    __syncthreads();
    if (t == 0){ coeff[i] = red[0] + red[2]; coeff[NL + i] = red[1] + red[3]; }
    __syncthreads();
  }
}

// ---------- LayerNorm -> bf16 xn (used once, after embed) ----------
__global__ __launch_bounds__(256) void ln_k(const float* __restrict__ hin,
    const float* __restrict__ g, const float* __restrict__ b,
    __hip_bfloat16* __restrict__ xn, int M)
{
  int lane = threadIdx.x & 63, wid = threadIdx.x >> 6;
  int n = blockIdx.x * 4 + wid;
  if (n >= M) return;
  const float* row = hin + (size_t)n * H;
  float x0 = row[lane], x1 = row[lane + 64];
  float mu = wsum(x0 + x1) * (1.f / H);
  float d0 = x0 - mu, d1 = x1 - mu;
  float var = wsum(d0 * d0 + d1 * d1) * (1.f / H);
  float rs = rsqrtf(var + 1e-5f);
  xn[(size_t)n * H + lane]      = __float2bfloat16(d0 * rs * g[lane]      + b[lane]);
  xn[(size_t)n * H + lane + 64] = __float2bfloat16(d1 * rs * g[lane + 64] + b[lane + 64]);
}

// ---------- dot product per node (wells only) ----------
__global__ __launch_bounds__(256) void dot2_k(const float* __restrict__ X,
    const float* __restrict__ va, float* __restrict__ oa, int M)
{
  int lane = threadIdx.x & 63, wid = threadIdx.x >> 6;
  int n = blockIdx.x * 4 + wid;
  if (n >= M) return;
  const float* row = X + (size_t)n * H;
  float a = wsum(row[lane] * va[lane] + row[lane + 64] * va[lane + 64]);
  if (lane == 0) oa[n] = a;
}

// ---------- MFMA GEMM (+fused attention dots, optional fp32/bf16 C) ----------
__global__ __launch_bounds__(512, 4) void gemm_mfma_k(
    const __hip_bfloat16* __restrict__ A, const __hip_bfloat16* __restrict__ WT,
    float* __restrict__ C, __hip_bfloat16* __restrict__ Cbf,
    const float* __restrict__ va, const float* __restrict__ vb,
    float* __restrict__ oa, float* __restrict__ ob, int M)
{
  __shared__ __hip_bfloat16 sX[128 * 128];
  __shared__ __hip_bfloat16 sW[128 * 128];
  const int tid = threadIdx.x;
  const int lane = tid & 63, w = tid >> 6;
  const int n0 = blockIdx.x * 128;
  const int rw = w * 16;
  const int lr = lane & 15, lk = lane >> 4;

  for (int c = tid; c < 2048; c += 512){
    int r = c >> 4, s = c & 15;
    int row = n0 + r;
    uint4 v = make_uint4(0u, 0u, 0u, 0u);
    if (row < M) v = *(const uint4*)(A + (size_t)row * 128 + s * 8);
    *(uint4*)((char*)sX + r * 256 + ((s * 16) ^ ((r & 7) << 4))) = v;
  }
  for (int c = tid; c < 2048; c += 512){
    int r = c >> 4, s = c & 15;
    uint4 v = *(const uint4*)(WT + (size_t)r * 128 + s * 8);
    *(uint4*)((char*)sW + r * 256 + ((s * 16) ^ ((r & 7) << 4))) = v;
  }
  __syncthreads();

  f32x4 acc[8];
  #pragma unroll
  for (int i = 0; i < 8; i++) acc[i] = (f32x4){0.f, 0.f, 0.f, 0.f};
  #pragma unroll
  for (int ks = 0; ks < 4; ks++){
    int arow = rw + lr;
    int ak = ks * 32 + lk * 8;
    bf16x8 a = *(const bf16x8*)((const char*)sX + arow * 256 + ((ak * 2) ^ ((arow & 7) << 4)));
    #pragma unroll
    for (int nt = 0; nt < 8; nt++){
      int brow = nt * 16 + lr;
      bf16x8 b = *(const bf16x8*)((const char*)sW + brow * 256 + ((ak * 2) ^ ((brow & 7) << 4)));
      acc[nt] = MFMA16(a, b, acc[nt]);
    }
  }
  #pragma unroll
  for (int nt = 0; nt < 8; nt++){
    int col = nt * 16 + lr;
    #pragma unroll
    for (int r = 0; r < 4; r++){
      int row = n0 + rw + lk * 4 + r;
      if (row < M){
        if (C)   C[(size_t)row * 128 + col] = acc[nt][r];
        if (Cbf) Cbf[(size_t)row * 128 + col] = __float2bfloat16(acc[nt][r]);
      }
    }
  }
  if (va){
    float vac[8], vbc[8];
    #pragma unroll
    for (int nt = 0; nt < 8; nt++){
      vac[nt] = va[nt * 16 + lr];
      vbc[nt] = vb ? vb[nt * 16 + lr] : 0.f;
    }
    #pragma unroll
    for (int r = 0; r < 4; r++){
      float da = 0.f, db = 0.f;
      #pragma unroll
      for (int nt = 0; nt < 8; nt++){
        da += acc[nt][r] * vac[nt];
        db += acc[nt][r] * vbc[nt];
      }
      #pragma unroll
      for (int o = 1; o < 16; o <<= 1){
        da += __shfl_xor(da, o, 64);
        db += __shfl_xor(db, o, 64);
      }
      int row = n0 + rw + lk * 4 + r;
      if (lr == 0 && row < M){
        oa[row] = da;
        if (ob) ob[row] = db;
      }
    }
  }
}

// ---------- MFMA fused FFN: h += relu(xn@W1+b1)@W2 + b2, epilogue LN or bf16 ----------
__global__ __launch_bounds__(512, 4) void ffn_mfma_k(
    const __hip_bfloat16* __restrict__ xn, float* __restrict__ h,
    const __hip_bfloat16* __restrict__ W1T, const float* __restrict__ b1,
    const __hip_bfloat16* __restrict__ W2T, const float* __restrict__ b2,
    const float* __restrict__ lng, const float* __restrict__ lnb,
    __hip_bfloat16* __restrict__ xout, int mode, int M)   // mode 0: LN->xout, 1: bf16->xout
{
  __shared__ __hip_bfloat16 sX[128 * 128];
  __shared__ __hip_bfloat16 sW1[DC * 128];
  __shared__ __hip_bfloat16 sW2[128 * DC];
  __shared__ __hip_bfloat16 sT[128 * DC];
  const int tid = threadIdx.x;
  const int lane = tid & 63, w = tid >> 6;
  const int n0 = blockIdx.x * 128;
  const int rw = w * 16;
  const int lr = lane & 15, lk = lane >> 4;

  for (int c = tid; c < 2048; c += 512){
    int r = c >> 4, s = c & 15;
    int row = n0 + r;
    uint4 v = make_uint4(0u, 0u, 0u, 0u);
    if (row < M) v = *(const uint4*)(xn + (size_t)row * 128 + s * 8);
    *(uint4*)((char*)sX + r * 256 + ((s * 16) ^ ((r & 7) << 4))) = v;
  }

  f32x4 acc2[8];
  #pragma unroll
  for (int i = 0; i < 8; i++) acc2[i] = (f32x4){0.f, 0.f, 0.f, 0.f};

  for (int ch = 0; ch < DFF / DC; ch++){
    __syncthreads();
    for (int c = tid; c < 1024; c += 512){
      int r = c >> 4, s = c & 15;
      uint4 v = *(const uint4*)(W1T + (size_t)(ch * DC + r) * 128 + s * 8);
      *(uint4*)((char*)sW1 + r * 256 + ((s * 16) ^ ((r & 7) << 4))) = v;
    }
    for (int c = tid; c < 1024; c += 512){
      int r = c >> 3, s = c & 7;
      uint4 v = *(const uint4*)(W2T + (size_t)r * DFF + ch * DC + s * 8);
      *(uint4*)((char*)sW2 + r * 128 + ((s * 16) ^ ((r & 7) << 4))) = v;
    }
    __syncthreads();

    f32x4 acc1[4];
    #pragma unroll
    for (int i = 0; i < 4; i++) acc1[i] = (f32x4){0.f, 0.f, 0.f, 0.f};
    #pragma unroll
    for (int ks = 0; ks < 4; ks++){
      int arow = rw + lr;
      int ak = ks * 32 + lk * 8;
      bf16x8 a = *(const bf16x8*)((const char*)sX + arow * 256 + ((ak * 2) ^ ((arow & 7) << 4)));
      #pragma unroll
      for (int nt = 0; nt < 4; nt++){
        int brow = nt * 16 + lr;
        bf16x8 b = *(const bf16x8*)((const char*)sW1 + brow * 256 + ((ak * 2) ^ ((brow & 7) << 4)));
        acc1[nt] = MFMA16(a, b, acc1[nt]);
      }
    }
    #pragma unroll
    for (int nt = 0; nt < 4; nt++){
      int col = nt * 16 + lr;
      float bb = b1[ch * DC + col];
      #pragma unroll
      for (int r = 0; r < 4; r++){
        int row = rw + lk * 4 + r;
        float v = fmaxf(acc1[nt][r] + bb, 0.f);
        *(__hip_bfloat16*)((char*)sT + row * 128 + ((col * 2) ^ ((row & 7) << 4))) =
            __float2bfloat16(v);
      }
    }
    asm volatile("s_waitcnt lgkmcnt(0)" ::: "memory");

    #pragma unroll
    for (int ks = 0; ks < 2; ks++){
      int arow = rw + lr;
      int ak = ks * 32 + lk * 8;
      bf16x8 a = *(const bf16x8*)((const char*)sT + arow * 128 + ((ak * 2) ^ ((arow & 7) << 4)));
      #pragma unroll
      for (int nt = 0; nt < 8; nt++){
        int brow = nt * 16 + lr;
        bf16x8 b = *(const bf16x8*)((const char*)sW2 + brow * 128 + ((ak * 2) ^ ((brow & 7) << 4)));
        acc2[nt] = MFMA16(a, b, acc2[nt]);
      }
    }
  }

  float b2c[8];
  #pragma unroll
  for (int nt = 0; nt < 8; nt++) b2c[nt] = b2[nt * 16 + lr];

  #pragma unroll
  for (int r = 0; r < 4; r++){
    int row = n0 + rw + lk * 4 + r;
    bool ok = row < M;
    float val[8]; float sum = 0.f;
    #pragma unroll
    for (int nt = 0; nt < 8; nt++){
      int col = nt * 16 + lr;
      float hv = ok ? h[(size_t)row * 128 + col] : 0.f;
      val[nt] = hv + acc2[nt][r] + b2c[nt];
      sum += val[nt];
    }
    if (mode == 0){
      #pragma unroll
      for (int o = 1; o < 16; o <<= 1) sum += __shfl_xor(sum, o, 64);
      float mu = sum * (1.f / 128.f);
      float vs = 0.f;
      #pragma unroll
      for (int nt = 0; nt < 8; nt++){ float d = val[nt] - mu; vs += d * d; }
      #pragma unroll
      for (int o = 1; o < 16; o <<= 1) vs += __shfl_xor(vs, o, 64);
      float rs = rsqrtf(vs * (1.f / 128.f) + 1e-5f);
      #pragma unroll
      for (int nt = 0; nt < 8; nt++){
        int col = nt * 16 + lr;
        if (ok){
          h[(size_t)row * 128 + col] = val[nt];
          xout[(size_t)row * 128 + col] =
              __float2bfloat16((val[nt] - mu) * rs * lng[col] + lnb[col]);
        }
      }
    } else {
      #pragma unroll
      for (int nt = 0; nt < 8; nt++){
        int col = nt * 16 + lr;
        if (ok){
          h[(size_t)row * 128 + col] = val[nt];
          xout[(size_t)row * 128 + col] = __float2bfloat16(val[nt]);
        }
      }
    }
  }
}

// ---------- fp32 GEMM (tiny well matmul) ----------
__global__ __launch_bounds__(256) void gemm128_k(const float* __restrict__ A,
    const float* __restrict__ Bm, float* __restrict__ C, int M)
{
  __shared__ float sB[32 * 128];
  __shared__ float sA[64 * 33];
  const int tid = threadIdx.x;
  const int n0 = blockIdx.x * 64;
  const int j4 = (tid & 31) * 4;
  const int rB = (tid >> 5) * 8;
  float acc[8][4];
  #pragma unroll
  for (int r = 0; r < 8; r++){ acc[r][0]=acc[r][1]=acc[r][2]=acc[r][3]=0.f; }
  for (int kc = 0; kc < 128; kc += 32){
    for (int t = tid; t < 4096; t += 256){
      int kk = t >> 7, j = t & 127;
      sB[kk * 128 + j] = Bm[(size_t)(kc + kk) * H + j];
    }
    for (int t = tid; t < 2048; t += 256){
      int n = t >> 5, kk = t & 31; int row = n0 + n;
      sA[n * 33 + kk] = (row < M) ? A[(size_t)row * H + kc + kk] : 0.f;
    }
    __syncthreads();
    #pragma unroll 8
    for (int kk = 0; kk < 32; kk++){
      float4 bv = *(const float4*)&sB[kk * 128 + j4];
      #pragma unroll
      for (int r = 0; r < 8; r++){
        float av = sA[(rB + r) * 33 + kk];
        acc[r][0] += av * bv.x; acc[r][1] += av * bv.y;
        acc[r][2] += av * bv.z; acc[r][3] += av * bv.w;
      }
    }
    __syncthreads();
  }
  #pragma unroll
  for (int r = 0; r < 8; r++){
    int row = n0 + rB + r;
    if (row < M){
      float4 o; o.x = acc[r][0]; o.y = acc[r][1]; o.z = acc[r][2]; o.w = acc[r][3];
      *(float4*)&C[(size_t)row * H + j4] = o;
    }
  }
}

// ---------- CSR build ----------
__global__ void count_k(const int* __restrict__ dst, int* __restrict__ cnt, int NE){
  int e = blockIdx.x * 256 + threadIdx.x;
  if (e < NE) atomicAdd(&cnt[dst[e]], 1);
}
__global__ void scan1_k(const int* __restrict__ in, int* __restrict__ out,
                        int* __restrict__ bsum, int N){
  __shared__ int sd[256];
  int tid = threadIdx.x;
  int base = blockIdx.x * 1024 + tid * 4;
  int v0 = (base + 0 < N) ? in[base + 0] : 0;
  int v1 = (base + 1 < N) ? in[base + 1] : 0;
  int v2 = (base + 2 < N) ? in[base + 2] : 0;
  int v3 = (base + 3 < N) ? in[base + 3] : 0;
  sd[tid] = v0 + v1 + v2 + v3;
  __syncthreads();
  for (int off = 1; off < 256; off <<= 1){
    int t = (tid >= off) ? sd[tid - off] : 0;
    __syncthreads();
    sd[tid] += t;
    __syncthreads();
  }
  int run = (tid > 0) ? sd[tid - 1] : 0;
  run += v0; if (base + 0 < N) out[base + 0] = run;
  run += v1; if (base + 1 < N) out[base + 1] = run;
  run += v2; if (base + 2 < N) out[base + 2] = run;
  run += v3; if (base + 3 < N) out[base + 3] = run;
  if (tid == 255) bsum[blockIdx.x] = sd[255];
}
__global__ void scan2_k(int* __restrict__ bs, int NB){
  __shared__ int sd[256];
  int tid = threadIdx.x;
  int base = tid * 4;
  int v0 = (base + 0 < NB) ? bs[base + 0] : 0;
  int v1 = (base + 1 < NB) ? bs[base + 1] : 0;
  int v2 = (base + 2 < NB) ? bs[base + 2] : 0;
  int v3 = (base + 3 < NB) ? bs[base + 3] : 0;
  sd[tid] = v0 + v1 + v2 + v3;
  __syncthreads();
  for (int off = 1; off < 256; off <<= 1){
    int t = (tid >= off) ? sd[tid - off] : 0;
    __syncthreads();
    sd[tid] += t;
    __syncthreads();
  }
  int run = (tid > 0) ? sd[tid - 1] : 0;
  run += v0; if (base + 0 < NB) bs[base + 0] = run;
  run += v1; if (base + 1 < NB) bs[base + 1] = run;
  run += v2; if (base + 2 < NB) bs[base + 2] = run;
  run += v3; if (base + 3 < NB) bs[base + 3] = run;
}
__global__ void scan3_k(int* __restrict__ out, const int* __restrict__ bsum, int N){
  int b = blockIdx.x;
  if (b == 0) return;
  int add = bsum[b - 1];
  int i = b * 1024 + threadIdx.x * 4;
  #pragma unroll
  for (int j = 0; j < 4; j++) if (i + j < N) out[i + j] += add;
}
__global__ void initfill_k(const int* __restrict__ incl, int* __restrict__ fill, int N){
  int i = blockIdx.x * 256 + threadIdx.x;
  if (i < N) fill[i] = (i == 0) ? 0 : incl[i - 1];
}
__global__ void fill_k(const int* __restrict__ dst, int* __restrict__ fill,
                       int* __restrict__ csr, int NE){
  int e = blockIdx.x * 256 + threadIdx.x;
  if (e < NE){
    int p = atomicAdd(&fill[dst[e]], 1);
    csr[p] = e;
  }
}

// ---------- fused GAT gather: 16-lane group per node (4 nodes/wave) ----------
__global__ __launch_bounds__(256) void gat_k(
    const int* __restrict__ incl, const int* __restrict__ csr,
    const int* __restrict__ src, const float* __restrict__ attr,
    const float* __restrict__ coeff, int ci,
    const float* __restrict__ as_, const float* __restrict__ ad_,
    const __hip_bfloat16* __restrict__ X, float* __restrict__ hout,
    const float* __restrict__ gb, const float* __restrict__ g,
    const float* __restrict__ b, __hip_bfloat16* __restrict__ xn,
    int M, int residual)
{
  int lane = threadIdx.x & 63, wid = threadIdx.x >> 6;
  int grp = lane >> 4, gl = lane & 15;
  int n = blockIdx.x * 16 + wid * 4 + grp;
  if (n >= M) return;
  int beg = (n == 0) ? 0 : incl[n - 1];
  int end = incl[n];
  float c0 = 0.f, c1 = 0.f;
  if (attr){ c0 = coeff[ci]; c1 = coeff[NL + ci]; }
  float adn = ad_[n];
  const int gbase = grp << 4;
  float m = -1e30f, s = 0.f;
  float acc[8];
  #pragma unroll
  for (int i = 0; i < 8; i++) acc[i] = 0.f;

  for (int base = beg; base < end; base += 16){
    int idx = base + gl;
    bool valid = idx < end;
    int e = valid ? csr[idx] : 0;
    int sv = valid ? src[e] : 0;
    float a = -1e30f;
    if (valid){
      a = as_[sv] + adn;
      if (attr) a += attr[e] * c0 + c1;
      a = (a > 0.f) ? a : 0.2f * a;
    }
    float cm = gmax16(a);
    float nm = fmaxf(m, cm);
    float sc = expf(m - nm);     // first chunk: exp(-inf) -> 0 (or 1 if still empty)
    #pragma unroll
    for (int i = 0; i < 8; i++) acc[i] *= sc;
    s *= sc;
    float p = valid ? expf(a - nm) : 0.f;
    s += gsum16(p);
    m = nm;
    int cnt = min(16, end - base);
    for (int t = 0; t < cnt; t++){
      float pt = __shfl(p, gbase + t, 64);
      int st = __shfl(sv, gbase + t, 64);
      uint4 u = *(const uint4*)(X + (size_t)st * H + gl * 8);
      acc[0] += pt * __uint_as_float(u.x << 16);
      acc[1] += pt * __uint_as_float(u.x & 0xffff0000u);
      acc[2] += pt * __uint_as_float(u.y << 16);
      acc[3] += pt * __uint_as_float(u.y & 0xffff0000u);
      acc[4] += pt * __uint_as_float(u.z << 16);
      acc[5] += pt * __uint_as_float(u.z & 0xffff0000u);
      acc[6] += pt * __uint_as_float(u.w << 16);
      acc[7] += pt * __uint_as_float(u.w & 0xffff0000u);
    }
  }
  float inv = (s == 0.f) ? 0.f : 1.f / s;
  int j0 = gl * 8;
  if (residual){
    float4 h0 = *(float4*)&hout[(size_t)n * H + j0];
    float4 h1 = *(float4*)&hout[(size_t)n * H + j0 + 4];
    float4 g0 = *(const float4*)&gb[j0];
    float4 g1 = *(const float4*)&gb[j0 + 4];
    float hv[8];
    hv[0] = h0.x + acc[0] * inv + g0.x; hv[1] = h0.y + acc[1] * inv + g0.y;
    hv[2] = h0.z + acc[2] * inv + g0.z; hv[3] = h0.w + acc[3] * inv + g0.w;
    hv[4] = h1.x + acc[4] * inv + g1.x; hv[5] = h1.y + acc[5] * inv + g1.y;
    hv[6] = h1.z + acc[6] * inv + g1.z; hv[7] = h1.w + acc[7] * inv + g1.w;
    float localsum = 0.f;
    #pragma unroll
    for (int i = 0; i < 8; i++) localsum += hv[i];
    float mu = gsum16(localsum) * (1.f / H);
    float vs = 0.f;
    #pragma unroll
    for (int i = 0; i < 8; i++){ float d = hv[i] - mu; vs += d * d; }
    float var = gsum16(vs) * (1.f / H);
    float rs = rsqrtf(var + 1e-5f);
    float4 o0, o1;
    o0.x = hv[0]; o0.y = hv[1]; o0.z = hv[2]; o0.w = hv[3];
    o1.x = hv[4]; o1.y = hv[5]; o1.z = hv[6]; o1.w = hv[7];
    *(float4*)&hout[(size_t)n * H + j0] = o0;
    *(float4*)&hout[(size_t)n * H + j0 + 4] = o1;
    float4 gg0 = *(const float4*)&g[j0];
    float4 gg1 = *(const float4*)&g[j0 + 4];
    float4 bb0 = *(const float4*)&b[j0];
    float4 bb1 = *(const float4*)&b[j0 + 4];
    float xo[8];
    xo[0] = (hv[0]-mu)*rs*gg0.x + bb0.x; xo[1] = (hv[1]-mu)*rs*gg0.y + bb0.y;
    xo[2] = (hv[2]-mu)*rs*gg0.z + bb0.z; xo[3] = (hv[3]-mu)*rs*gg0.w + bb0.w;
    xo[4] = (hv[4]-mu)*rs*gg1.x + bb1.x; xo[5] = (hv[5]-mu)*rs*gg1.y + bb1.y;
    xo[6] = (hv[6]-mu)*rs*gg1.z + bb1.z; xo[7] = (hv[7]-mu)*rs*gg1.w + bb1.w;
    uint4 ow;
    unsigned* owp = (unsigned*)&ow;
    #pragma unroll
    for (int i = 0; i < 4; i++){
      __hip_bfloat16 lo = __float2bfloat16(xo[2*i]);
      __hip_bfloat16 hi = __float2bfloat16(xo[2*i+1]);
      owp[i] = ((unsigned)(*(unsigned short*)&hi) << 16) | (*(unsigned short*)&lo);
    }
    *(uint4*)((char*)xn + ((size_t)n * H + j0) * 2) = ow;
  } else {
    float4 o0, o1;
    o0.x = acc[0]*inv; o0.y = acc[1]*inv; o0.z = acc[2]*inv; o0.w = acc[3]*inv;
    o1.x = acc[4]*inv; o1.y = acc[5]*inv; o1.z = acc[6]*inv; o1.w = acc[7]*inv;
    *(float4*)&hout[(size_t)n * H + j0] = o0;
    *(float4*)&hout[(size_t)n * H + j0 + 4] = o1;
  }
}

// ---------- final well MLP ----------
__global__ __launch_bounds__(128) void mlp_k(const float* __restrict__ hwell,
    const float* __restrict__ wb, const float* __restrict__ mW1,
    const float* __restrict__ mb1, const float* __restrict__ mW2,
    const float* __restrict__ mb2, float* __restrict__ out)
{
  __shared__ float sH[128], sT[128];
  int n = blockIdx.x, j = threadIdx.x;
  sH[j] = hwell[(size_t)n * H + j] + wb[j];
  __syncthreads();
  float a = mb1[j];
  for (int k = 0; k < 128; k++) a += sH[k] * mW1[k * 128 + j];
  sT[j] = fmaxf(a, 0.f);
  __syncthreads();
  if (j < 75){
    float o = mb2[j];
    for (int k = 0; k < 128; k++) o += sT[k] * mW2[k * 75 + j];
    out[(size_t)n * 75 + j] = o;
  }
}

extern "C" void kernel_launch(void* const* d_in, const int* in_sizes, int n_in,
                              void* d_out, int out_size, void* d_ws, size_t ws_size,
                              hipStream_t stream)
{
  (void)in_sizes; (void)n_in; (void)out_size; (void)ws_size;
  const float* cell_x = (const float*)d_in[0];
  const float* well_x = (const float*)d_in[1];
  const int*   eidx   = (const int*)d_in[2];
  const float* eattr  = (const float*)d_in[3];
  const int*   wsrc   = (const int*)d_in[4];
  const int*   wdst   = (const int*)d_in[5];
  const float* W_cell = (const float*)d_in[6];
  const float* b_cell = (const float*)d_in[7];
  const float* W_well = (const float*)d_in[8];
  const float* b_well = (const float*)d_in[9];
  const float* W_ee   = (const float*)d_in[10];
  const float* b_ee   = (const float*)d_in[11];
  const float* gW     = (const float*)d_in[12];
  const float* gas    = (const float*)d_in[13];
  const float* gad    = (const float*)d_in[14];
  const float* gae    = (const float*)d_in[15];
  const float* gWe    = (const float*)d_in[16];
  const float* gb     = (const float*)d_in[17];
  const float* n1g    = (const float*)d_in[18];
  const float* n1b    = (const float*)d_in[19];
  const float* fW1    = (const float*)d_in[20];
  const float* fb1    = (const float*)d_in[21];
  const float* fW2    = (const float*)d_in[22];
  const float* fb2    = (const float*)d_in[23];
  const float* n2g    = (const float*)d_in[24];
  const float* n2b    = (const float*)d_in[25];
  const float* wW     = (const float*)d_in[26];
  const float* was    = (const float*)d_in[27];
  const float* wad    = (const float*)d_in[28];
  const float* wb     = (const float*)d_in[29];
  const float* mW1    = (const float*)d_in[30];
  const float* mb1    = (const float*)d_in[31];
  const float* mW2    = (const float*)d_in[32];
  const float* mb2    = (const float*)d_in[33];

  const int* src = eidx;
  const int* dst = eidx + NE_CC;

  char* wsb = (char*)d_ws;
  size_t off = 0;
  auto alloc = [&](size_t bytes) -> void* {
    void* p = wsb + off; off += (bytes + 255) & ~(size_t)255; return p;
  };
  float* h      = (float*)alloc((size_t)NC * H * 4);
  __hip_bfloat16* xnbf = (__hip_bfloat16*)alloc((size_t)NC * H * 2);
  __hip_bfloat16* hsbf = (__hip_bfloat16*)alloc((size_t)NC * H * 2);
  float* as_    = (float*)alloc((size_t)NC * 4);
  float* ad_    = (float*)alloc((size_t)NC * 4);
  float* hw     = (float*)alloc((size_t)NW * H * 4);
  float* hwp    = (float*)alloc((size_t)NW * H * 4);
  float* hwell  = (float*)alloc((size_t)NW * H * 4);
  float* coeff  = (float*)alloc(64);
  __hip_bfloat16* gWT = (__hip_bfloat16*)alloc((size_t)NL * H * H * 2);
  __hip_bfloat16* W1T = (__hip_bfloat16*)alloc((size_t)NL * DFF * H * 2);
  __hip_bfloat16* W2T = (__hip_bfloat16*)alloc((size_t)NL * H * DFF * 2);
  __hip_bfloat16* wWT = (__hip_bfloat16*)alloc((size_t)H * H * 2);
  int* cntC  = (int*)alloc((size_t)NC * 4);
  int* inclC = (int*)alloc((size_t)NC * 4);
  int* fillC = (int*)alloc((size_t)NC * 4);
  int* csrC  = (int*)alloc((size_t)NE_CC * 4);
  int* inclW = (int*)alloc((size_t)NW * 4);
  int* fillW = (int*)alloc((size_t)NW * 4);
  int* csrW  = (int*)alloc((size_t)NE_CW * 4);
  int* bsum  = (int*)alloc(1024 * 4);

  const int eBlocks  = (NE_CC + 255) / 256;
  const int ewBlocks = (NE_CW + 255) / 256;
  const int NBC = (NC + 1023) / 1024;
  const int NBW = (NW + 1023) / 1024;

  // ---- CSR build (c2c) ----
  hipMemsetAsync(cntC, 0, (size_t)NC * 4, stream);
  count_k<<<eBlocks, 256, 0, stream>>>(dst, cntC, NE_CC);
  scan1_k<<<NBC, 256, 0, stream>>>(cntC, inclC, bsum, NC);
  scan2_k<<<1, 256, 0, stream>>>(bsum, NBC);
  scan3_k<<<NBC, 256, 0, stream>>>(inclC, bsum, NC);
  initfill_k<<<(NC + 255) / 256, 256, 0, stream>>>(inclC, fillC, NC);
  fill_k<<<eBlocks, 256, 0, stream>>>(dst, fillC, csrC, NE_CC);
  // ---- CSR build (c2w) ----
  hipMemsetAsync(fillW, 0, (size_t)NW * 4, stream);
  count_k<<<ewBlocks, 256, 0, stream>>>(wdst, fillW, NE_CW);
  scan1_k<<<NBW, 256, 0, stream>>>(fillW, inclW, bsum, NW);
  scan2_k<<<1, 256, 0, stream>>>(bsum, NBW);
  scan3_k<<<NBW, 256, 0, stream>>>(inclW, bsum, NW);
  initfill_k<<<(NW + 255) / 256, 256, 0, stream>>>(inclW, fillW, NW);
  fill_k<<<ewBlocks, 256, 0, stream>>>(wdst, fillW, csrW, NE_CW);

  // ---- weight prep ----
  prep_T_k<<<192, 256, 0, stream>>>(gW, gWT, 128, 128, NL);
  prep_T_k<<<768, 256, 0, stream>>>(fW1, W1T, 128, 512, NL);
  prep_T_k<<<768, 256, 0, stream>>>(fW2, W2T, 512, 128, NL);
  prep_T_k<<<64, 256, 0, stream>>>(wW, wWT, 128, 128, 1);

  embed_k<32><<<2048, 256, 0, stream>>>(cell_x, W_cell, b_cell, h, NC);
  embed_k<16><<<250, 256, 0, stream>>>(well_x, W_well, b_well, hw, NW);
  coeff_k<<<1, 128, 0, stream>>>(gWe, gae, W_ee, b_ee, coeff);

  const int lnBlocks = (NC + 3) / 4;
  const int mfmaBlocks = (NC + 127) / 128;
  const int gatBlocks = (NC + 15) / 16;

  ln_k<<<lnBlocks, 256, 0, stream>>>(h, n1g, n1b, xnbf, NC);  // layer-0 LN1

  for (int i = 0; i < NL; i++){
    gemm_mfma_k<<<mfmaBlocks, 512, 0, stream>>>(xnbf, gWT + (size_t)i * H * H,
        nullptr, hsbf, gas + i * H, gad + i * H, as_, ad_, NC);
    gat_k<<<gatBlocks, 256, 0, stream>>>(inclC, csrC, src, eattr, coeff, i,
        as_, ad_, hsbf, h, gb + i * H, n2g + i * H, n2b + i * H, xnbf, NC, 1);
    int last = (i == NL - 1);
    ffn_mfma_k<<<mfmaBlocks, 512, 0, stream>>>(xnbf, h,
        W1T + (size_t)i * DFF * H, fb1 + (size_t)i * DFF,
        W2T + (size_t)i * H * DFF, fb2 + (size_t)i * H,
        n1g + ((i + 1) % NL) * H, n1b + ((i + 1) % NL) * H,
        xnbf, last ? 1 : 0, NC);
  }

  // cell -> well bipartite GAT (xnbf now holds bf16(h))
  gemm_mfma_k<<<mfmaBlocks, 512, 0, stream>>>(xnbf, wWT,
      nullptr, hsbf, was, nullptr, as_, nullptr, NC);            // hc(bf16) + as_
  gemm128_k<<<(NW + 63) / 64, 256, 0, stream>>>(hw, wW, hwp, NW);
  dot2_k<<<(NW + 3) / 4, 256, 0, stream>>>(hwp, wad, ad_, NW);
  gat_k<<<(NW + 15) / 16, 256, 0, stream>>>(inclW, csrW, wsrc, nullptr, coeff, 0,
      as_, ad_, hsbf, hwell, nullptr, nullptr, nullptr, nullptr, NW, 0);
  mlp_k<<<NW, 128, 0, stream>>>(hwell, wb, mW1, mb1, mW2, mb2, (float*)d_out);
}